// Round 4
// baseline (177.298 us; speedup 1.0000x reference)
//
#include <hip/hip_runtime.h>
#include <hip/hip_bf16.h>

// ---------------------------------------------------------------------------
// ClusterGNN fused pipeline for MI355X (gfx950).  Round 1.
//   - k_mlp split into 3 kernels (was 62us latency-bound on 16 blocks).
//   - k_conv re-tiled to exploit logits symmetry: 32x32 pair tiles, upper
//     triangle only (36 tiles/cluster), stats weighted x2 off-diagonal,
//     logits mirror-written.  q-rows in registers, p-rows in 4KB LDS.
// ---------------------------------------------------------------------------

typedef short bfrag8 __attribute__((ext_vector_type(8)));   // 8 bf16 (4 VGPR)
typedef float f32x4  __attribute__((ext_vector_type(4)));

#define DI __device__ __forceinline__

DI unsigned short f2bf(float f) {
  return __builtin_bit_cast(unsigned short, __float2bfloat16(f));
}
DI float bf2f(unsigned short u) {
  return __builtin_bit_cast(float, ((unsigned)u) << 16);
}

// ------------------------------- pool --------------------------------------
__global__ __launch_bounds__(256) void k_pool(const float* __restrict__ xc,
                                              float* __restrict__ x) {
  int idx = blockIdx.x * 256 + threadIdx.x;      // 131072 = 4096*32
  int c = idx & 31, g = idx >> 5;
  int gz = g & 15, gy = (g >> 4) & 15, gx = g >> 8;
  float s = 0.f;
  for (int ix = 0; ix < 4; ++ix)
    for (int iy = 0; iy < 4; ++iy)
      for (int iz = 0; iz < 4; ++iz) {
        int X = gx * 4 + ix, Y = gy * 4 + iy, Z = gz * 4 + iz;
        s += xc[(size_t)(((X << 6) | Y) << 6 | Z) * 32 + c];
      }
  x[idx] = s * (1.f / 64.f);
}

// --------------------------- order + gather --------------------------------
__global__ __launch_bounds__(256) void k_order(const int* __restrict__ ci,
                                               const float* __restrict__ x,
                                               int* __restrict__ order,
                                               float* __restrict__ xi) {
  const int k = blockIdx.x, t = threadIdx.x;
  __shared__ int scnt[256];
  __shared__ int ordl[256];
  int match[16];
  int cnt = 0;
#pragma unroll
  for (int j = 0; j < 16; ++j) { match[j] = (ci[t * 16 + j] == k); cnt += match[j]; }
  scnt[t] = cnt;
  __syncthreads();
  for (int off = 1; off < 256; off <<= 1) {        // inclusive Hillis-Steele
    int v = (t >= off) ? scnt[t - off] : 0;
    __syncthreads();
    scnt[t] += v;
    __syncthreads();
  }
  int pos = scnt[t] - cnt;                         // exclusive
#pragma unroll
  for (int j = 0; j < 16; ++j)
    if (match[j]) ordl[pos++] = t * 16 + j;
  __syncthreads();
  int src = ordl[t];
  order[k * 256 + t] = src;
  const f32x4* xr = (const f32x4*)(x + (size_t)src * 32);
  f32x4* xo = (f32x4*)(xi + ((size_t)k * 256 + t) * 32);
#pragma unroll
  for (int c = 0; c < 8; ++c) xo[c] = xr[c];
}

// ---------------------------- weight cvt -----------------------------------
__global__ __launch_bounds__(256) void k_wcvt(const float* __restrict__ w1,
                                              const float* __restrict__ w2,
                                              unsigned short* __restrict__ w1b,
                                              unsigned short* __restrict__ w2b) {
  int i = blockIdx.x * 256 + threadIdx.x;
  if (i < 32768) w1b[i] = f2bf(w1[i]);
  if (i < 98304) w2b[i] = f2bf(w2[i]);
}

// ------------------------------- MLP (split) --------------------------------
__global__ __launch_bounds__(256) void k_mlp1(
    const float* __restrict__ xi,
    const float* __restrict__ mw1, const float* __restrict__ mb1,
    const float* __restrict__ mw2, const float* __restrict__ mb2,
    float* __restrict__ h2buf) {
  const int k = blockIdx.x, t = threadIdx.x;
  __shared__ float red[256];
  __shared__ float cent[32];
  __shared__ float h1[128];
  const float* xk = xi + (size_t)k * 8192;
  {
    int c = t & 31, rp = t >> 5;
    float ssum = 0.f;
    for (int r = rp; r < 256; r += 8) ssum += xk[r * 32 + c];
    red[t] = ssum;
  }
  __syncthreads();
  if (t < 32) {
    float tot = 0.f;
#pragma unroll
    for (int g = 0; g < 8; ++g) tot += red[g * 32 + t];
    cent[t] = tot * (1.f / 256.f);
  }
  __syncthreads();
  if (t < 128) {
    float s = mb1[t];
#pragma unroll
    for (int c = 0; c < 32; ++c) s += cent[c] * mw1[c * 128 + t];
    h1[t] = fmaxf(s, 0.f);
  }
  __syncthreads();
  float s = mb2[t];
  for (int j = 0; j < 128; ++j) s += h1[j] * mw2[j * 256 + t];
  h2buf[k * 256 + t] = fmaxf(s, 0.f);
}

__global__ __launch_bounds__(256) void k_mlp2(
    const float* __restrict__ h2buf,
    const float* __restrict__ mw3, const float* __restrict__ mb3,
    float* __restrict__ swb) {
  const int k = blockIdx.y, t = threadIdx.x;
  const int o = blockIdx.x * 256 + t;
  __shared__ float h2s[256];
  h2s[t] = h2buf[k * 256 + t];
  __syncthreads();
  float s = mb3[o];
  for (int j = 0; j < 256; ++j) s += h2s[j] * mw3[j * 1024 + o];
  swb[k * 1024 + o] = 1.f / (1.f + __expf(-s));
}

__global__ __launch_bounds__(256) void k_mlp3(
    const float* __restrict__ swb,
    const float* __restrict__ gcnw,
    float* __restrict__ weff) {
  const int k = blockIdx.y, t = threadIdx.x;
  const int e = blockIdx.x * 256 + t;           // 0..2047
  __shared__ float swl[1024];
#pragma unroll
  for (int j = 0; j < 4; ++j) swl[t + j * 256] = swb[k * 1024 + t + j * 256];
  __syncthreads();
  const int u = e >> 5, v = e & 31;
  const float* gk = gcnw + (size_t)k * 2048;
  float s = 0.f;
#pragma unroll
  for (int ss = 0; ss < 32; ++ss) s += gk[u * 32 + ss] * swl[ss * 32 + v];
  weff[(size_t)k * 2048 + e] = s;
}

// --------------------------- fused pair chain -------------------------------
// Symmetric tiling: per cluster, 36 tiles (a<=b) of 32p x 32q.  Block = 4
// waves; wave wv handles p in [Pb+8wv, Pb+8wv+8), all 32 q-rows.  q-rows in
// registers, p-rows in LDS.  Stats weighted (1 diag / 2 off-diag); logits
// mirror-written for off-diag tiles.
template <int MODE>
__global__ __launch_bounds__(256) void k_conv(
    const float* __restrict__ xi,
    const unsigned short* __restrict__ w1b,
    const unsigned short* __restrict__ w2b,
    const float2* __restrict__ coef1,
    const float2* __restrict__ coef2,
    const float* __restrict__ conv3w,
    float* __restrict__ stats1,
    float* __restrict__ stats2,
    float* __restrict__ logits) {
  const int k   = blockIdx.y;
  const int t36 = blockIdx.x;            // 0..35 upper-triangle tile
  int a = 0, rem = t36;
  while (rem >= 8 - a) { rem -= 8 - a; ++a; }
  const int b = a + rem;                 // a<=b
  const int Pb = a * 32, Qb = b * 32;
  const float w = (a == b) ? 1.f : 2.f;

  const int tid = threadIdx.x;
  const int lane = tid & 63;
  const int wv  = tid >> 6;              // wave 0..3
  const int l15 = lane & 15;
  const int lg  = lane >> 4;             // 0..3

  __shared__ __align__(16) float xp[32][32];                 // p rows
  constexpr int NF = (MODE == 0) ? 4 : 6;
  constexpr int A1SZ = (MODE >= 1) ? 4 * 32 * 72 : 8;
  __shared__ __align__(16) unsigned short a1s[A1SZ];
  __shared__ float sred[192];

  const float* xik = xi + (size_t)k * (256 * 32);

  {  // stage 32 p rows
    const int r = tid >> 3, c4 = (tid & 7) * 4;
    *(f32x4*)&xp[r][c4] = *(const f32x4*)(xik + (size_t)(Pb + r) * 32 + c4);
  }

  // q rows in registers: rows Qb+rt*16+l15, cols lg*8..+8
  float qv[2][8];
#pragma unroll
  for (int rt = 0; rt < 2; ++rt) {
    const float* qr = xik + (size_t)(Qb + rt * 16 + l15) * 32 + lg * 8;
    f32x4 v0 = *(const f32x4*)qr;
    f32x4 v1 = *(const f32x4*)(qr + 4);
#pragma unroll
    for (int j = 0; j < 4; ++j) { qv[rt][j] = v0[j]; qv[rt][4 + j] = v1[j]; }
  }

  // B fragments / coefficients (per-lane, L2 resident)
  bfrag8 B1[4];
  {
    const unsigned short* w1k = w1b + k * (64 * 32);
#pragma unroll
    for (int f = 0; f < 4; ++f)
      B1[f] = *(const bfrag8*)(w1k + (16 * f + l15) * 32 + lg * 8);
  }
  bfrag8 B2[6][2];
  float2 c1[4];
  float2 c2[6];
  float w3v[6];
  if constexpr (MODE >= 1) {
    const unsigned short* w2k = w2b + k * (96 * 64);
#pragma unroll
    for (int f = 0; f < 6; ++f) {
      B2[f][0] = *(const bfrag8*)(w2k + (16 * f + l15) * 64 + lg * 8);
      B2[f][1] = *(const bfrag8*)(w2k + (16 * f + l15) * 64 + 32 + lg * 8);
    }
#pragma unroll
    for (int f = 0; f < 4; ++f) c1[f] = coef1[k * 64 + 16 * f + l15];
  }
  if constexpr (MODE == 2) {
#pragma unroll
    for (int f = 0; f < 6; ++f) {
      c2[f]  = coef2[k * 96 + 16 * f + l15];
      w3v[f] = conv3w[k * 96 + 16 * f + l15];
    }
  }

  float ssum[6], ssq[6];
#pragma unroll
  for (int f = 0; f < 6; ++f) { ssum[f] = 0.f; ssq[f] = 0.f; }

  __syncthreads();

  for (int pl = 0; pl < 8; ++pl) {
    const int plocal = wv * 8 + pl;
    const int pglob  = Pb + plocal;
    float pv[8];
    {
      const float* xpp = &xp[plocal][lg * 8];
#pragma unroll
      for (int j = 0; j < 8; ++j) pv[j] = xpp[j];
    }
#pragma unroll
    for (int rt = 0; rt < 2; ++rt) {
      bfrag8 af;
#pragma unroll
      for (int j = 0; j < 8; ++j) af[j] = (short)f2bf(fabsf(qv[rt][j] - pv[j]));
      const f32x4 z = {0.f, 0.f, 0.f, 0.f};
      f32x4 acc1[4];
#pragma unroll
      for (int f = 0; f < 4; ++f)
        acc1[f] = __builtin_amdgcn_mfma_f32_16x16x32_bf16(af, B1[f], z, 0, 0, 0);
      if constexpr (MODE == 0) {
#pragma unroll
        for (int f = 0; f < 4; ++f)
#pragma unroll
          for (int r = 0; r < 4; ++r) { float h = acc1[f][r]; ssum[f] += h; ssq[f] += h * h; }
      } else {
        unsigned short* aw = &a1s[wv * 2304 + (rt * 16 + lg * 4) * 72 + l15];
#pragma unroll
        for (int f = 0; f < 4; ++f)
#pragma unroll
          for (int r = 0; r < 4; ++r) {
            float h = acc1[f][r] * c1[f].x + c1[f].y;
            h = fmaxf(h, 0.2f * h);
            aw[r * 72 + 16 * f] = f2bf(h);
          }
      }
    }
    if constexpr (MODE >= 1) {
#pragma unroll
      for (int rt = 0; rt < 2; ++rt) {
        bfrag8 A0 = *(const bfrag8*)&a1s[wv * 2304 + (rt * 16 + l15) * 72 + lg * 8];
        bfrag8 A1 = *(const bfrag8*)&a1s[wv * 2304 + (rt * 16 + l15) * 72 + 32 + lg * 8];
        f32x4 acc2[6];
#pragma unroll
        for (int f = 0; f < 6; ++f) {
          f32x4 acc = {0.f, 0.f, 0.f, 0.f};
          acc = __builtin_amdgcn_mfma_f32_16x16x32_bf16(A0, B2[f][0], acc, 0, 0, 0);
          acc = __builtin_amdgcn_mfma_f32_16x16x32_bf16(A1, B2[f][1], acc, 0, 0, 0);
          acc2[f] = acc;
        }
        if constexpr (MODE == 1) {
#pragma unroll
          for (int f = 0; f < 6; ++f)
#pragma unroll
            for (int r = 0; r < 4; ++r) { float h = acc2[f][r]; ssum[f] += h; ssq[f] += h * h; }
        } else {
          f32x4 lp = {0.f, 0.f, 0.f, 0.f};
#pragma unroll
          for (int f = 0; f < 6; ++f)
#pragma unroll
            for (int r = 0; r < 4; ++r) {
              float h = acc2[f][r] * c2[f].x + c2[f].y;
              h = fmaxf(h, 0.2f * h);
              lp[r] += h * w3v[f];
            }
#pragma unroll
          for (int m = 1; m < 16; m <<= 1) {
            lp[0] += __shfl_xor(lp[0], m);
            lp[1] += __shfl_xor(lp[1], m);
            lp[2] += __shfl_xor(lp[2], m);
            lp[3] += __shfl_xor(lp[3], m);
          }
          if (l15 == 0) {
            const int q0 = Qb + rt * 16 + lg * 4;
            *(f32x4*)&logits[(size_t)k * 65536 + (size_t)pglob * 256 + q0] = lp;
            if (a != b) {
#pragma unroll
              for (int r = 0; r < 4; ++r)
                logits[(size_t)k * 65536 + (size_t)(q0 + r) * 256 + pglob] = lp[r];
            }
          }
        }
      }
    }
  }

  if constexpr (MODE <= 1) {
#pragma unroll
    for (int f = 0; f < NF; ++f) {
      ssum[f] += __shfl_xor(ssum[f], 16); ssum[f] += __shfl_xor(ssum[f], 32);
      ssq[f]  += __shfl_xor(ssq[f], 16);  ssq[f]  += __shfl_xor(ssq[f], 32);
    }
    __syncthreads();
    if (tid < 2 * 16 * NF) sred[tid] = 0.f;
    __syncthreads();
    if (lg == 0) {
#pragma unroll
      for (int f = 0; f < NF; ++f) {
        atomicAdd(&sred[(16 * f + l15) * 2 + 0], ssum[f] * w);
        atomicAdd(&sred[(16 * f + l15) * 2 + 1], ssq[f] * w);
      }
    }
    __syncthreads();
    float* gs = (MODE == 0) ? stats1 : stats2;
    if (tid < 2 * 16 * NF) atomicAdd(&gs[k * (2 * 16 * NF) + tid], sred[tid]);
  }
}

// ------------------------- BN coefficient kernel ----------------------------
__global__ void k_bnco(const float* __restrict__ stats,
                       const float* __restrict__ g,
                       const float* __restrict__ b,
                       float2* __restrict__ coef, int nch) {
  int i = blockIdx.x * 256 + threadIdx.x;
  if (i >= 16 * nch) return;
  float sum = stats[i * 2], sq = stats[i * 2 + 1];
  const float invN = 1.f / 65536.f;
  float mean = sum * invN;
  float var = sq * invN - mean * mean;
  float s = g[i] * rsqrtf(fmaxf(var, 0.f) + 1e-5f);
  coef[i] = make_float2(s, b[i] - mean * s);
}

// --------------------- softmax + adj@xi + GCN + BN3 stats -------------------
__global__ __launch_bounds__(256) void k_graph(
    const float* __restrict__ xi,
    const float* __restrict__ logits,
    const float* __restrict__ weff,
    float* __restrict__ hi,
    float* __restrict__ stats3) {
  const int k  = blockIdx.y;
  const int pc = blockIdx.x;   // 0..7, 32 rows each
  const int tid = threadIdx.x;
  __shared__ unsigned short xis[256 * 36];   // bf16 xi, pad 36
  __shared__ float es[32][258];
  __shared__ float axs[32][33];
  __shared__ float inv_s[32];
  __shared__ float s3[64];

  const float* xik = xi + (size_t)k * 8192;
  for (int i = tid; i < 8192; i += 256) {
    int r = i >> 5, c = i & 31;
    xis[r * 36 + c] = f2bf(xik[i]);
  }
  if (tid < 64) s3[tid] = 0.f;
  __syncthreads();

  const int row = tid >> 3;    // 0..31
  const int s   = tid & 7;
  const int pglob = pc * 32 + row;
  const float* lrow = logits + (size_t)k * 65536 + (size_t)pglob * 256;

  float m = -1e30f;
  for (int q = s; q < 256; q += 8) {
    float v = lrow[q];
    m = (q == pglob) ? m : fmaxf(m, v);
  }
  m = fmaxf(m, __shfl_xor(m, 1));
  m = fmaxf(m, __shfl_xor(m, 2));
  m = fmaxf(m, __shfl_xor(m, 4));
  float sum = 0.f;
  for (int q = s; q < 256; q += 8) {
    float e = (q == pglob) ? 0.f : __expf(lrow[q] - m);
    es[row][q] = e;
    sum += e;
  }
  sum += __shfl_xor(sum, 1);
  sum += __shfl_xor(sum, 2);
  sum += __shfl_xor(sum, 4);
  if (s == 0) inv_s[row] = 1.f / sum;
  __syncthreads();

  const int c0 = s * 4;
  float a0 = 0.f, a1 = 0.f, a2 = 0.f, a3 = 0.f;
  for (int q = 0; q < 256; ++q) {
    float e = es[row][q];
    const unsigned short* xr = &xis[q * 36 + c0];
    a0 += e * bf2f(xr[0]);
    a1 += e * bf2f(xr[1]);
    a2 += e * bf2f(xr[2]);
    a3 += e * bf2f(xr[3]);
  }
  float iv = inv_s[row];
  axs[row][c0 + 0] = a0 * iv; axs[row][c0 + 1] = a1 * iv;
  axs[row][c0 + 2] = a2 * iv; axs[row][c0 + 3] = a3 * iv;
  __syncthreads();

  const float* wk = weff + (size_t)k * 2048;
  float h[4] = {0.f, 0.f, 0.f, 0.f};
  for (int u = 0; u < 32; ++u) {
    float xu = bf2f(xis[pglob * 36 + u]);
    float au = axs[row][u];
    const float* w0 = wk + u * 32 + c0;
    const float* w1 = wk + (32 + u) * 32 + c0;
#pragma unroll
    for (int j = 0; j < 4; ++j) h[j] += xu * w0[j] + au * w1[j];
  }
  float* hrow = hi + (size_t)k * 8192 + (size_t)pglob * 32 + c0;
  float vs[4], vq[4];
#pragma unroll
  for (int j = 0; j < 4; ++j) {
    float v = fmaxf(h[j], 0.2f * h[j]);
    hrow[j] = v;
    vs[j] = v; vq[j] = v * v;
  }
#pragma unroll
  for (int j = 0; j < 4; ++j) {
#pragma unroll
    for (int mm = 8; mm < 64; mm <<= 1) {
      vs[j] += __shfl_xor(vs[j], mm);
      vq[j] += __shfl_xor(vq[j], mm);
    }
  }
  if ((tid & 56) == 0) {
#pragma unroll
    for (int j = 0; j < 4; ++j) {
      atomicAdd(&s3[(c0 + j) * 2 + 0], vs[j]);
      atomicAdd(&s3[(c0 + j) * 2 + 1], vq[j]);
    }
  }
  __syncthreads();
  if (tid < 64) atomicAdd(&stats3[k * 64 + tid], s3[tid]);
}

// ------------------------------ BN3 + scatter -------------------------------
__global__ __launch_bounds__(256) void k_bn3(
    const float* __restrict__ hi, const float* __restrict__ stats3,
    const float* __restrict__ g3, const float* __restrict__ b3,
    const int* __restrict__ order, float* __restrict__ xnew) {
  int idx = blockIdx.x * 256 + threadIdx.x;   // 131072
  int k = idx >> 13, r = (idx >> 5) & 255, c = idx & 31;
  float sum = stats3[k * 64 + c * 2], sq = stats3[k * 64 + c * 2 + 1];
  const float invN = 1.f / 256.f;
  float mean = sum * invN;
  float var = sq * invN - mean * mean;
  float s = g3[k * 32 + c] * rsqrtf(fmaxf(var, 0.f) + 1e-5f);
  float t = b3[k * 32 + c] - mean * s;
  xnew[(size_t)order[k * 256 + r] * 32 + c] = hi[idx] * s + t;
}

// ------------------------------- final add ----------------------------------
__global__ __launch_bounds__(256) void k_final(const float* __restrict__ xc,
                                               const float* __restrict__ xnew,
                                               float* __restrict__ out) {
  int idx = blockIdx.x * 256 + threadIdx.x;   // 2097152 float4 groups
  int c4 = idx & 7, v = idx >> 3;
  int z = v & 63, y = (v >> 6) & 63, x = v >> 12;
  int sx = (x >> 2) + (x & 3) - 1;
  int sy = (y >> 2) + (y & 3) - 1;
  int sz = (z >> 2) + (z & 3) - 1;
  f32x4 add = {0.f, 0.f, 0.f, 0.f};
  if ((unsigned)sx < 16u && (unsigned)sy < 16u && (unsigned)sz < 16u)
    add = *(const f32x4*)&xnew[(size_t)(((sx << 4) + sy) * 16 + sz) * 32 + c4 * 4];
  const f32x4 a = *(const f32x4*)&xc[(size_t)idx * 4];
  *(f32x4*)&out[(size_t)idx * 4] = a + add;
}

// ----------------------------------------------------------------------------
extern "C" void kernel_launch(void* const* d_in, const int* in_sizes, int n_in,
                              void* d_out, int out_size, void* d_ws, size_t ws_size,
                              hipStream_t stream) {
  const float* xc   = (const float*)d_in[0];
  const int*   ci   = (const int*)  d_in[1];
  const float* c1w  = (const float*)d_in[2];
  const float* bn1g = (const float*)d_in[4];
  const float* bn1b = (const float*)d_in[5];
  const float* c2w  = (const float*)d_in[6];
  const float* bn2g = (const float*)d_in[8];
  const float* bn2b = (const float*)d_in[9];
  const float* c3w  = (const float*)d_in[10];
  const float* gcnw = (const float*)d_in[12];
  const float* bn3g = (const float*)d_in[13];
  const float* bn3b = (const float*)d_in[14];
  const float* mw1  = (const float*)d_in[15];
  const float* mb1  = (const float*)d_in[16];
  const float* mw2  = (const float*)d_in[17];
  const float* mb2  = (const float*)d_in[18];
  const float* mw3  = (const float*)d_in[19];
  const float* mb3  = (const float*)d_in[20];

  float* wsf = (float*)d_ws;
  float*  x      = wsf + 0;          // 131072 (dead after k_order; reused below)
  float*  xi     = wsf + 131072;     // 131072
  float*  xnew   = wsf + 262144;     // 131072
  float*  hi     = wsf + 393216;     // 131072
  float*  weff   = wsf + 524288;     // 32768
  float*  stats1 = wsf + 557056;     // 2048
  float*  stats2 = wsf + 559104;     // 3072
  float*  stats3 = wsf + 562176;     // 1024
  float2* coef1  = (float2*)(wsf + 563200);  // 2048 floats
  float2* coef2  = (float2*)(wsf + 565248);  // 3072 floats
  float*  logits = wsf + 568320;     // 1048576
  unsigned char* wsb = (unsigned char*)d_ws;
  int* order = (int*)(wsb + 6467584);
  unsigned short* w1b = (unsigned short*)(wsb + 6467584 + 16384);
  unsigned short* w2b = (unsigned short*)(wsb + 6467584 + 16384 + 65536);
  // MLP scratch aliases the dead x region (x consumed by k_order before k_mlp1)
  float* h2mlp = x;                  // 4096 floats
  float* swb   = x + 4096;           // 16384 floats

  hipMemsetAsync(stats1, 0, 6144 * sizeof(float), stream);  // stats1|2|3
  k_pool <<<512, 256, 0, stream>>>(xc, x);
  k_wcvt <<<384, 256, 0, stream>>>(c1w, c2w, w1b, w2b);
  k_order<<<16, 256, 0, stream>>>(ci, x, order, xi);
  k_mlp1 <<<16, 256, 0, stream>>>(xi, mw1, mb1, mw2, mb2, h2mlp);
  k_mlp2 <<<dim3(4, 16), 256, 0, stream>>>(h2mlp, mw3, mb3, swb);
  k_mlp3 <<<dim3(8, 16), 256, 0, stream>>>(swb, gcnw, weff);
  dim3 gconv(36, 16);
  k_conv<0><<<gconv, 256, 0, stream>>>(xi, w1b, w2b, coef1, coef2, c3w, stats1, stats2, logits);
  k_bnco <<<4, 256, 0, stream>>>(stats1, bn1g, bn1b, coef1, 64);
  k_conv<1><<<gconv, 256, 0, stream>>>(xi, w1b, w2b, coef1, coef2, c3w, stats1, stats2, logits);
  k_bnco <<<6, 256, 0, stream>>>(stats2, bn2g, bn2b, coef2, 96);
  k_conv<2><<<gconv, 256, 0, stream>>>(xi, w1b, w2b, coef1, coef2, c3w, stats1, stats2, logits);
  k_graph<<<dim3(8, 16), 256, 0, stream>>>(xi, logits, weff, hi, stats3);
  k_bn3  <<<512, 256, 0, stream>>>(hi, stats3, bn3g, bn3b, order, xnew);
  k_final<<<8192, 256, 0, stream>>>(xc, xnew, (float*)d_out);
}

// Round 5
// 176.896 us; speedup vs baseline: 1.0023x; 1.0023x over previous
//
#include <hip/hip_runtime.h>
#include <hip/hip_bf16.h>

// ---------------------------------------------------------------------------
// ClusterGNN fused pipeline for MI355X (gfx950).  Round 1.
//   - k_mlp split into 3 kernels (was 62us latency-bound on 16 blocks).
//   - k_conv re-tiled to exploit logits symmetry: 32x32 pair tiles, upper
//     triangle only (36 tiles/cluster), stats weighted x2 off-diagonal,
//     logits mirror-written.  q-rows in registers, p-rows in 4KB LDS.
// ---------------------------------------------------------------------------

typedef short bfrag8 __attribute__((ext_vector_type(8)));   // 8 bf16 (4 VGPR)
typedef float f32x4  __attribute__((ext_vector_type(4)));

#define DI __device__ __forceinline__

DI unsigned short f2bf(float f) {
  return __builtin_bit_cast(unsigned short, __float2bfloat16(f));
}
DI float bf2f(unsigned short u) {
  return __builtin_bit_cast(float, ((unsigned)u) << 16);
}

// ------------------------------- pool --------------------------------------
__global__ __launch_bounds__(256) void k_pool(const float* __restrict__ xc,
                                              float* __restrict__ x) {
  int idx = blockIdx.x * 256 + threadIdx.x;      // 131072 = 4096*32
  int c = idx & 31, g = idx >> 5;
  int gz = g & 15, gy = (g >> 4) & 15, gx = g >> 8;
  float s = 0.f;
  for (int ix = 0; ix < 4; ++ix)
    for (int iy = 0; iy < 4; ++iy)
      for (int iz = 0; iz < 4; ++iz) {
        int X = gx * 4 + ix, Y = gy * 4 + iy, Z = gz * 4 + iz;
        s += xc[(size_t)(((X << 6) | Y) << 6 | Z) * 32 + c];
      }
  x[idx] = s * (1.f / 64.f);
}

// --------------------------- order + gather --------------------------------
__global__ __launch_bounds__(256) void k_order(const int* __restrict__ ci,
                                               const float* __restrict__ x,
                                               int* __restrict__ order,
                                               float* __restrict__ xi) {
  const int k = blockIdx.x, t = threadIdx.x;
  __shared__ int scnt[256];
  __shared__ int ordl[256];
  int match[16];
  int cnt = 0;
#pragma unroll
  for (int j = 0; j < 16; ++j) { match[j] = (ci[t * 16 + j] == k); cnt += match[j]; }
  scnt[t] = cnt;
  __syncthreads();
  for (int off = 1; off < 256; off <<= 1) {        // inclusive Hillis-Steele
    int v = (t >= off) ? scnt[t - off] : 0;
    __syncthreads();
    scnt[t] += v;
    __syncthreads();
  }
  int pos = scnt[t] - cnt;                         // exclusive
#pragma unroll
  for (int j = 0; j < 16; ++j)
    if (match[j]) ordl[pos++] = t * 16 + j;
  __syncthreads();
  int src = ordl[t];
  order[k * 256 + t] = src;
  const f32x4* xr = (const f32x4*)(x + (size_t)src * 32);
  f32x4* xo = (f32x4*)(xi + ((size_t)k * 256 + t) * 32);
#pragma unroll
  for (int c = 0; c < 8; ++c) xo[c] = xr[c];
}

// ---------------------------- weight cvt -----------------------------------
__global__ __launch_bounds__(256) void k_wcvt(const float* __restrict__ w1,
                                              const float* __restrict__ w2,
                                              unsigned short* __restrict__ w1b,
                                              unsigned short* __restrict__ w2b) {
  int i = blockIdx.x * 256 + threadIdx.x;
  if (i < 32768) w1b[i] = f2bf(w1[i]);
  if (i < 98304) w2b[i] = f2bf(w2[i]);
}

// ------------------------------- MLP (split) --------------------------------
__global__ __launch_bounds__(256) void k_mlp1(
    const float* __restrict__ xi,
    const float* __restrict__ mw1, const float* __restrict__ mb1,
    const float* __restrict__ mw2, const float* __restrict__ mb2,
    float* __restrict__ h2buf) {
  const int k = blockIdx.x, t = threadIdx.x;
  __shared__ float red[256];
  __shared__ float cent[32];
  __shared__ float h1[128];
  const float* xk = xi + (size_t)k * 8192;
  {
    int c = t & 31, rp = t >> 5;
    float ssum = 0.f;
    for (int r = rp; r < 256; r += 8) ssum += xk[r * 32 + c];
    red[t] = ssum;
  }
  __syncthreads();
  if (t < 32) {
    float tot = 0.f;
#pragma unroll
    for (int g = 0; g < 8; ++g) tot += red[g * 32 + t];
    cent[t] = tot * (1.f / 256.f);
  }
  __syncthreads();
  if (t < 128) {
    float s = mb1[t];
#pragma unroll
    for (int c = 0; c < 32; ++c) s += cent[c] * mw1[c * 128 + t];
    h1[t] = fmaxf(s, 0.f);
  }
  __syncthreads();
  float s = mb2[t];
  for (int j = 0; j < 128; ++j) s += h1[j] * mw2[j * 256 + t];
  h2buf[k * 256 + t] = fmaxf(s, 0.f);
}

__global__ __launch_bounds__(256) void k_mlp2(
    const float* __restrict__ h2buf,
    const float* __restrict__ mw3, const float* __restrict__ mb3,
    float* __restrict__ swb) {
  const int k = blockIdx.y, t = threadIdx.x;
  const int o = blockIdx.x * 256 + t;
  __shared__ float h2s[256];
  h2s[t] = h2buf[k * 256 + t];
  __syncthreads();
  float s = mb3[o];
  for (int j = 0; j < 256; ++j) s += h2s[j] * mw3[j * 1024 + o];
  swb[k * 1024 + o] = 1.f / (1.f + __expf(-s));
}

__global__ __launch_bounds__(256) void k_mlp3(
    const float* __restrict__ swb,
    const float* __restrict__ gcnw,
    float* __restrict__ weff) {
  const int k = blockIdx.y, t = threadIdx.x;
  const int e = blockIdx.x * 256 + t;           // 0..2047
  __shared__ float swl[1024];
#pragma unroll
  for (int j = 0; j < 4; ++j) swl[t + j * 256] = swb[k * 1024 + t + j * 256];
  __syncthreads();
  const int u = e >> 5, v = e & 31;
  const float* gk = gcnw + (size_t)k * 2048;
  float s = 0.f;
#pragma unroll
  for (int ss = 0; ss < 32; ++ss) s += gk[u * 32 + ss] * swl[ss * 32 + v];
  weff[(size_t)k * 2048 + e] = s;
}

// --------------------------- fused pair chain -------------------------------
// Symmetric tiling: per cluster, 36 tiles (a<=b) of 32p x 32q.  Block = 4
// waves; wave wv handles p in [Pb+8wv, Pb+8wv+8), all 32 q-rows.  q-rows in
// registers, p-rows in LDS.  Stats weighted (1 diag / 2 off-diag); logits
// mirror-written for off-diag tiles.
template <int MODE>
__global__ __launch_bounds__(256) void k_conv(
    const float* __restrict__ xi,
    const unsigned short* __restrict__ w1b,
    const unsigned short* __restrict__ w2b,
    const float2* __restrict__ coef1,
    const float2* __restrict__ coef2,
    const float* __restrict__ conv3w,
    float* __restrict__ stats1,
    float* __restrict__ stats2,
    float* __restrict__ logits) {
  const int k   = blockIdx.y;
  const int t36 = blockIdx.x;            // 0..35 upper-triangle tile
  int a = 0, rem = t36;
  while (rem >= 8 - a) { rem -= 8 - a; ++a; }
  const int b = a + rem;                 // a<=b
  const int Pb = a * 32, Qb = b * 32;
  const float w = (a == b) ? 1.f : 2.f;

  const int tid = threadIdx.x;
  const int lane = tid & 63;
  const int wv  = tid >> 6;              // wave 0..3
  const int l15 = lane & 15;
  const int lg  = lane >> 4;             // 0..3

  __shared__ __align__(16) float xp[32][32];                 // p rows
  constexpr int NF = (MODE == 0) ? 4 : 6;
  constexpr int A1SZ = (MODE >= 1) ? 4 * 32 * 72 : 8;
  __shared__ __align__(16) unsigned short a1s[A1SZ];
  __shared__ float sred[192];

  const float* xik = xi + (size_t)k * (256 * 32);

  {  // stage 32 p rows
    const int r = tid >> 3, c4 = (tid & 7) * 4;
    *(f32x4*)&xp[r][c4] = *(const f32x4*)(xik + (size_t)(Pb + r) * 32 + c4);
  }

  // q rows in registers: rows Qb+rt*16+l15, cols lg*8..+8
  float qv[2][8];
#pragma unroll
  for (int rt = 0; rt < 2; ++rt) {
    const float* qr = xik + (size_t)(Qb + rt * 16 + l15) * 32 + lg * 8;
    f32x4 v0 = *(const f32x4*)qr;
    f32x4 v1 = *(const f32x4*)(qr + 4);
#pragma unroll
    for (int j = 0; j < 4; ++j) { qv[rt][j] = v0[j]; qv[rt][4 + j] = v1[j]; }
  }

  // B fragments / coefficients (per-lane, L2 resident)
  bfrag8 B1[4];
  {
    const unsigned short* w1k = w1b + k * (64 * 32);
#pragma unroll
    for (int f = 0; f < 4; ++f)
      B1[f] = *(const bfrag8*)(w1k + (16 * f + l15) * 32 + lg * 8);
  }
  bfrag8 B2[6][2];
  float2 c1[4];
  float2 c2[6];
  float w3v[6];
  if constexpr (MODE >= 1) {
    const unsigned short* w2k = w2b + k * (96 * 64);
#pragma unroll
    for (int f = 0; f < 6; ++f) {
      B2[f][0] = *(const bfrag8*)(w2k + (16 * f + l15) * 64 + lg * 8);
      B2[f][1] = *(const bfrag8*)(w2k + (16 * f + l15) * 64 + 32 + lg * 8);
    }
#pragma unroll
    for (int f = 0; f < 4; ++f) c1[f] = coef1[k * 64 + 16 * f + l15];
  }
  if constexpr (MODE == 2) {
#pragma unroll
    for (int f = 0; f < 6; ++f) {
      c2[f]  = coef2[k * 96 + 16 * f + l15];
      w3v[f] = conv3w[k * 96 + 16 * f + l15];
    }
  }

  float ssum[6], ssq[6];
#pragma unroll
  for (int f = 0; f < 6; ++f) { ssum[f] = 0.f; ssq[f] = 0.f; }

  __syncthreads();

  for (int pl = 0; pl < 8; ++pl) {
    const int plocal = wv * 8 + pl;
    const int pglob  = Pb + plocal;
    float pv[8];
    {
      const float* xpp = &xp[plocal][lg * 8];
#pragma unroll
      for (int j = 0; j < 8; ++j) pv[j] = xpp[j];
    }
#pragma unroll
    for (int rt = 0; rt < 2; ++rt) {
      bfrag8 af;
#pragma unroll
      for (int j = 0; j < 8; ++j) af[j] = (short)f2bf(fabsf(qv[rt][j] - pv[j]));
      const f32x4 z = {0.f, 0.f, 0.f, 0.f};
      f32x4 acc1[4];
#pragma unroll
      for (int f = 0; f < 4; ++f)
        acc1[f] = __builtin_amdgcn_mfma_f32_16x16x32_bf16(af, B1[f], z, 0, 0, 0);
      if constexpr (MODE == 0) {
#pragma unroll
        for (int f = 0; f < 4; ++f)
#pragma unroll
          for (int r = 0; r < 4; ++r) { float h = acc1[f][r]; ssum[f] += h; ssq[f] += h * h; }
      } else {
        unsigned short* aw = &a1s[wv * 2304 + (rt * 16 + lg * 4) * 72 + l15];
#pragma unroll
        for (int f = 0; f < 4; ++f)
#pragma unroll
          for (int r = 0; r < 4; ++r) {
            float h = acc1[f][r] * c1[f].x + c1[f].y;
            h = fmaxf(h, 0.2f * h);
            aw[r * 72 + 16 * f] = f2bf(h);
          }
      }
    }
    if constexpr (MODE >= 1) {
#pragma unroll
      for (int rt = 0; rt < 2; ++rt) {
        bfrag8 A0 = *(const bfrag8*)&a1s[wv * 2304 + (rt * 16 + l15) * 72 + lg * 8];
        bfrag8 A1 = *(const bfrag8*)&a1s[wv * 2304 + (rt * 16 + l15) * 72 + 32 + lg * 8];
        f32x4 acc2[6];
#pragma unroll
        for (int f = 0; f < 6; ++f) {
          f32x4 acc = {0.f, 0.f, 0.f, 0.f};
          acc = __builtin_amdgcn_mfma_f32_16x16x32_bf16(A0, B2[f][0], acc, 0, 0, 0);
          acc = __builtin_amdgcn_mfma_f32_16x16x32_bf16(A1, B2[f][1], acc, 0, 0, 0);
          acc2[f] = acc;
        }
        if constexpr (MODE == 1) {
#pragma unroll
          for (int f = 0; f < 6; ++f)
#pragma unroll
            for (int r = 0; r < 4; ++r) { float h = acc2[f][r]; ssum[f] += h; ssq[f] += h * h; }
        } else {
          f32x4 lp = {0.f, 0.f, 0.f, 0.f};
#pragma unroll
          for (int f = 0; f < 6; ++f)
#pragma unroll
            for (int r = 0; r < 4; ++r) {
              float h = acc2[f][r] * c2[f].x + c2[f].y;
              h = fmaxf(h, 0.2f * h);
              lp[r] += h * w3v[f];
            }
#pragma unroll
          for (int m = 1; m < 16; m <<= 1) {
            lp[0] += __shfl_xor(lp[0], m);
            lp[1] += __shfl_xor(lp[1], m);
            lp[2] += __shfl_xor(lp[2], m);
            lp[3] += __shfl_xor(lp[3], m);
          }
          if (l15 == 0) {
            const int q0 = Qb + rt * 16 + lg * 4;
            *(f32x4*)&logits[(size_t)k * 65536 + (size_t)pglob * 256 + q0] = lp;
            if (a != b) {
#pragma unroll
              for (int r = 0; r < 4; ++r)
                logits[(size_t)k * 65536 + (size_t)(q0 + r) * 256 + pglob] = lp[r];
            }
          }
        }
      }
    }
  }

  if constexpr (MODE <= 1) {
#pragma unroll
    for (int f = 0; f < NF; ++f) {
      ssum[f] += __shfl_xor(ssum[f], 16); ssum[f] += __shfl_xor(ssum[f], 32);
      ssq[f]  += __shfl_xor(ssq[f], 16);  ssq[f]  += __shfl_xor(ssq[f], 32);
    }
    __syncthreads();
    if (tid < 2 * 16 * NF) sred[tid] = 0.f;
    __syncthreads();
    if (lg == 0) {
#pragma unroll
      for (int f = 0; f < NF; ++f) {
        atomicAdd(&sred[(16 * f + l15) * 2 + 0], ssum[f] * w);
        atomicAdd(&sred[(16 * f + l15) * 2 + 1], ssq[f] * w);
      }
    }
    __syncthreads();
    float* gs = (MODE == 0) ? stats1 : stats2;
    if (tid < 2 * 16 * NF) atomicAdd(&gs[k * (2 * 16 * NF) + tid], sred[tid]);
  }
}

// ------------------------- BN coefficient kernel ----------------------------
__global__ void k_bnco(const float* __restrict__ stats,
                       const float* __restrict__ g,
                       const float* __restrict__ b,
                       float2* __restrict__ coef, int nch) {
  int i = blockIdx.x * 256 + threadIdx.x;
  if (i >= 16 * nch) return;
  float sum = stats[i * 2], sq = stats[i * 2 + 1];
  const float invN = 1.f / 65536.f;
  float mean = sum * invN;
  float var = sq * invN - mean * mean;
  float s = g[i] * rsqrtf(fmaxf(var, 0.f) + 1e-5f);
  coef[i] = make_float2(s, b[i] - mean * s);
}

// --------------------- softmax + adj@xi + GCN + BN3 stats -------------------
__global__ __launch_bounds__(256) void k_graph(
    const float* __restrict__ xi,
    const float* __restrict__ logits,
    const float* __restrict__ weff,
    float* __restrict__ hi,
    float* __restrict__ stats3) {
  const int k  = blockIdx.y;
  const int pc = blockIdx.x;   // 0..7, 32 rows each
  const int tid = threadIdx.x;
  __shared__ unsigned short xis[256 * 36];   // bf16 xi, pad 36
  __shared__ float es[32][258];
  __shared__ float axs[32][33];
  __shared__ float inv_s[32];
  __shared__ float s3[64];

  const float* xik = xi + (size_t)k * 8192;
  for (int i = tid; i < 8192; i += 256) {
    int r = i >> 5, c = i & 31;
    xis[r * 36 + c] = f2bf(xik[i]);
  }
  if (tid < 64) s3[tid] = 0.f;
  __syncthreads();

  const int row = tid >> 3;    // 0..31
  const int s   = tid & 7;
  const int pglob = pc * 32 + row;
  const float* lrow = logits + (size_t)k * 65536 + (size_t)pglob * 256;

  float m = -1e30f;
  for (int q = s; q < 256; q += 8) {
    float v = lrow[q];
    m = (q == pglob) ? m : fmaxf(m, v);
  }
  m = fmaxf(m, __shfl_xor(m, 1));
  m = fmaxf(m, __shfl_xor(m, 2));
  m = fmaxf(m, __shfl_xor(m, 4));
  float sum = 0.f;
  for (int q = s; q < 256; q += 8) {
    float e = (q == pglob) ? 0.f : __expf(lrow[q] - m);
    es[row][q] = e;
    sum += e;
  }
  sum += __shfl_xor(sum, 1);
  sum += __shfl_xor(sum, 2);
  sum += __shfl_xor(sum, 4);
  if (s == 0) inv_s[row] = 1.f / sum;
  __syncthreads();

  const int c0 = s * 4;
  float a0 = 0.f, a1 = 0.f, a2 = 0.f, a3 = 0.f;
  for (int q = 0; q < 256; ++q) {
    float e = es[row][q];
    const unsigned short* xr = &xis[q * 36 + c0];
    a0 += e * bf2f(xr[0]);
    a1 += e * bf2f(xr[1]);
    a2 += e * bf2f(xr[2]);
    a3 += e * bf2f(xr[3]);
  }
  float iv = inv_s[row];
  axs[row][c0 + 0] = a0 * iv; axs[row][c0 + 1] = a1 * iv;
  axs[row][c0 + 2] = a2 * iv; axs[row][c0 + 3] = a3 * iv;
  __syncthreads();

  const float* wk = weff + (size_t)k * 2048;
  float h[4] = {0.f, 0.f, 0.f, 0.f};
  for (int u = 0; u < 32; ++u) {
    float xu = bf2f(xis[pglob * 36 + u]);
    float au = axs[row][u];
    const float* w0 = wk + u * 32 + c0;
    const float* w1 = wk + (32 + u) * 32 + c0;
#pragma unroll
    for (int j = 0; j < 4; ++j) h[j] += xu * w0[j] + au * w1[j];
  }
  float* hrow = hi + (size_t)k * 8192 + (size_t)pglob * 32 + c0;
  float vs[4], vq[4];
#pragma unroll
  for (int j = 0; j < 4; ++j) {
    float v = fmaxf(h[j], 0.2f * h[j]);
    hrow[j] = v;
    vs[j] = v; vq[j] = v * v;
  }
#pragma unroll
  for (int j = 0; j < 4; ++j) {
#pragma unroll
    for (int mm = 8; mm < 64; mm <<= 1) {
      vs[j] += __shfl_xor(vs[j], mm);
      vq[j] += __shfl_xor(vq[j], mm);
    }
  }
  if ((tid & 56) == 0) {
#pragma unroll
    for (int j = 0; j < 4; ++j) {
      atomicAdd(&s3[(c0 + j) * 2 + 0], vs[j]);
      atomicAdd(&s3[(c0 + j) * 2 + 1], vq[j]);
    }
  }
  __syncthreads();
  if (tid < 64) atomicAdd(&stats3[k * 64 + tid], s3[tid]);
}

// ------------------------------ BN3 + scatter -------------------------------
__global__ __launch_bounds__(256) void k_bn3(
    const float* __restrict__ hi, const float* __restrict__ stats3,
    const float* __restrict__ g3, const float* __restrict__ b3,
    const int* __restrict__ order, float* __restrict__ xnew) {
  int idx = blockIdx.x * 256 + threadIdx.x;   // 131072
  int k = idx >> 13, r = (idx >> 5) & 255, c = idx & 31;
  float sum = stats3[k * 64 + c * 2], sq = stats3[k * 64 + c * 2 + 1];
  const float invN = 1.f / 256.f;
  float mean = sum * invN;
  float var = sq * invN - mean * mean;
  float s = g3[k * 32 + c] * rsqrtf(fmaxf(var, 0.f) + 1e-5f);
  float t = b3[k * 32 + c] - mean * s;
  xnew[(size_t)order[k * 256 + r] * 32 + c] = hi[idx] * s + t;
}

// ------------------------------- final add ----------------------------------
__global__ __launch_bounds__(256) void k_final(const float* __restrict__ xc,
                                               const float* __restrict__ xnew,
                                               float* __restrict__ out) {
  int idx = blockIdx.x * 256 + threadIdx.x;   // 2097152 float4 groups
  int c4 = idx & 7, v = idx >> 3;
  int z = v & 63, y = (v >> 6) & 63, x = v >> 12;
  int sx = (x >> 2) + (x & 3) - 1;
  int sy = (y >> 2) + (y & 3) - 1;
  int sz = (z >> 2) + (z & 3) - 1;
  f32x4 add = {0.f, 0.f, 0.f, 0.f};
  if ((unsigned)sx < 16u && (unsigned)sy < 16u && (unsigned)sz < 16u)
    add = *(const f32x4*)&xnew[(size_t)(((sx << 4) + sy) * 16 + sz) * 32 + c4 * 4];
  const f32x4 a = *(const f32x4*)&xc[(size_t)idx * 4];
  *(f32x4*)&out[(size_t)idx * 4] = a + add;
}

// ----------------------------------------------------------------------------
extern "C" void kernel_launch(void* const* d_in, const int* in_sizes, int n_in,
                              void* d_out, int out_size, void* d_ws, size_t ws_size,
                              hipStream_t stream) {
  const float* xc   = (const float*)d_in[0];
  const int*   ci   = (const int*)  d_in[1];
  const float* c1w  = (const float*)d_in[2];
  const float* bn1g = (const float*)d_in[4];
  const float* bn1b = (const float*)d_in[5];
  const float* c2w  = (const float*)d_in[6];
  const float* bn2g = (const float*)d_in[8];
  const float* bn2b = (const float*)d_in[9];
  const float* c3w  = (const float*)d_in[10];
  const float* gcnw = (const float*)d_in[12];
  const float* bn3g = (const float*)d_in[13];
  const float* bn3b = (const float*)d_in[14];
  const float* mw1  = (const float*)d_in[15];
  const float* mb1  = (const float*)d_in[16];
  const float* mw2  = (const float*)d_in[17];
  const float* mb2  = (const float*)d_in[18];
  const float* mw3  = (const float*)d_in[19];
  const float* mb3  = (const float*)d_in[20];

  float* wsf = (float*)d_ws;
  float*  x      = wsf + 0;          // 131072 (dead after k_order; reused below)
  float*  xi     = wsf + 131072;     // 131072
  float*  xnew   = wsf + 262144;     // 131072
  float*  hi     = wsf + 393216;     // 131072
  float*  weff   = wsf + 524288;     // 32768
  float*  stats1 = wsf + 557056;     // 2048
  float*  stats2 = wsf + 559104;     // 3072
  float*  stats3 = wsf + 562176;     // 1024
  float2* coef1  = (float2*)(wsf + 563200);  // 2048 floats
  float2* coef2  = (float2*)(wsf + 565248);  // 3072 floats
  float*  logits = wsf + 568320;     // 1048576
  unsigned char* wsb = (unsigned char*)d_ws;
  int* order = (int*)(wsb + 6467584);
  unsigned short* w1b = (unsigned short*)(wsb + 6467584 + 16384);
  unsigned short* w2b = (unsigned short*)(wsb + 6467584 + 16384 + 65536);
  // MLP scratch aliases the dead x region (x consumed by k_order before k_mlp1)
  float* h2mlp = x;                  // 4096 floats
  float* swb   = x + 4096;           // 16384 floats

  hipMemsetAsync(stats1, 0, 6144 * sizeof(float), stream);  // stats1|2|3
  k_pool <<<512, 256, 0, stream>>>(xc, x);
  k_wcvt <<<384, 256, 0, stream>>>(c1w, c2w, w1b, w2b);
  k_order<<<16, 256, 0, stream>>>(ci, x, order, xi);
  k_mlp1 <<<16, 256, 0, stream>>>(xi, mw1, mb1, mw2, mb2, h2mlp);
  k_mlp2 <<<dim3(4, 16), 256, 0, stream>>>(h2mlp, mw3, mb3, swb);
  k_mlp3 <<<dim3(8, 16), 256, 0, stream>>>(swb, gcnw, weff);
  dim3 gconv(36, 16);
  k_conv<0><<<gconv, 256, 0, stream>>>(xi, w1b, w2b, coef1, coef2, c3w, stats1, stats2, logits);
  k_bnco <<<4, 256, 0, stream>>>(stats1, bn1g, bn1b, coef1, 64);
  k_conv<1><<<gconv, 256, 0, stream>>>(xi, w1b, w2b, coef1, coef2, c3w, stats1, stats2, logits);
  k_bnco <<<6, 256, 0, stream>>>(stats2, bn2g, bn2b, coef2, 96);
  k_conv<2><<<gconv, 256, 0, stream>>>(xi, w1b, w2b, coef1, coef2, c3w, stats1, stats2, logits);
  k_graph<<<dim3(8, 16), 256, 0, stream>>>(xi, logits, weff, hi, stats3);
  k_bn3  <<<512, 256, 0, stream>>>(hi, stats3, bn3g, bn3b, order, xnew);
  k_final<<<8192, 256, 0, stream>>>(xc, xnew, (float*)d_out);
}

// Round 6
// 169.043 us; speedup vs baseline: 1.0488x; 1.0465x over previous
//
#include <hip/hip_runtime.h>
#include <hip/hip_bf16.h>

// ---------------------------------------------------------------------------
// ClusterGNN fused pipeline for MI355X (gfx950).  Round 6.
//   k_conv rewritten: swapped-operand MFMA (h1^T = w1@d^T) + permuted-K w2 so
//   GEMM2 fragments come straight from GEMM1 accumulators (no LDS transpose,
//   no LDS at all in the main loop).  bn2+lrelu+w3-dot folded to per-channel
//   (A,B,sg): out = 0.6a + sg*|a|, a = A*h2+B.  1152 blocks (was 576).
// ---------------------------------------------------------------------------

typedef short bfrag8 __attribute__((ext_vector_type(8)));   // 8 bf16 (4 VGPR)
typedef float f32x4  __attribute__((ext_vector_type(4)));

#define DI __device__ __forceinline__

DI unsigned short f2bf(float f) {
  return __builtin_bit_cast(unsigned short, __float2bfloat16(f));
}
DI float bf2f(unsigned short u) {
  return __builtin_bit_cast(float, ((unsigned)u) << 16);
}

// ------------------------------- pool --------------------------------------
__global__ __launch_bounds__(256) void k_pool(const float* __restrict__ xc,
                                              float* __restrict__ x) {
  int idx = blockIdx.x * 256 + threadIdx.x;      // 32768 = 4096*8 float4s
  int c4 = idx & 7, g = idx >> 3;
  int gz = g & 15, gy = (g >> 4) & 15, gx = g >> 8;
  f32x4 s = {0.f, 0.f, 0.f, 0.f};
  for (int ix = 0; ix < 4; ++ix)
    for (int iy = 0; iy < 4; ++iy)
      for (int iz = 0; iz < 4; ++iz) {
        int X = gx * 4 + ix, Y = gy * 4 + iy, Z = gz * 4 + iz;
        s += *(const f32x4*)&xc[(size_t)(((X << 6) | Y) << 6 | Z) * 32 + c4 * 4];
      }
  *(f32x4*)&x[(size_t)idx * 4] = s * (1.f / 64.f);
}

// --------------------------- order + gather --------------------------------
__global__ __launch_bounds__(256) void k_order(const int* __restrict__ ci,
                                               const float* __restrict__ x,
                                               int* __restrict__ order,
                                               float* __restrict__ xi) {
  const int k = blockIdx.x, t = threadIdx.x;
  __shared__ int scnt[256];
  __shared__ int ordl[256];
  int match[16];
  int cnt = 0;
#pragma unroll
  for (int j = 0; j < 16; ++j) { match[j] = (ci[t * 16 + j] == k); cnt += match[j]; }
  scnt[t] = cnt;
  __syncthreads();
  for (int off = 1; off < 256; off <<= 1) {
    int v = (t >= off) ? scnt[t - off] : 0;
    __syncthreads();
    scnt[t] += v;
    __syncthreads();
  }
  int pos = scnt[t] - cnt;
#pragma unroll
  for (int j = 0; j < 16; ++j)
    if (match[j]) ordl[pos++] = t * 16 + j;
  __syncthreads();
  int src = ordl[t];
  order[k * 256 + t] = src;
  const f32x4* xr = (const f32x4*)(x + (size_t)src * 32);
  f32x4* xo = (f32x4*)(xi + ((size_t)k * 256 + t) * 32);
#pragma unroll
  for (int c = 0; c < 8; ++c) xo[c] = xr[c];
}

// ---------------------------- weight cvt + permute --------------------------
// w2p[o2][s*32+kp] = w2[o2][32s + 16*((kp>>2)&1) + 4*(kp>>3) + (kp&3)]
__global__ __launch_bounds__(256) void k_wcvt(const float* __restrict__ w1,
                                              const float* __restrict__ w2,
                                              unsigned short* __restrict__ w1b,
                                              unsigned short* __restrict__ w2p) {
  int i = blockIdx.x * 256 + threadIdx.x;
  if (i < 32768) w1b[i] = f2bf(w1[i]);
  if (i < 98304) {
    int o = i >> 6, cc = i & 63;
    int s = cc >> 5, kp = cc & 31;
    int src = 32 * s + 16 * ((kp >> 2) & 1) + 4 * (kp >> 3) + (kp & 3);
    w2p[i] = f2bf(w2[(size_t)o * 64 + src]);
  }
}

// ------------------------------- MLP (split) --------------------------------
__global__ __launch_bounds__(256) void k_mlp1(
    const float* __restrict__ xi,
    const float* __restrict__ mw1, const float* __restrict__ mb1,
    const float* __restrict__ mw2, const float* __restrict__ mb2,
    float* __restrict__ h2buf) {
  const int k = blockIdx.x, t = threadIdx.x;
  __shared__ float red[256];
  __shared__ float cent[32];
  __shared__ float h1[128];
  const float* xk = xi + (size_t)k * 8192;
  {
    int c = t & 31, rp = t >> 5;
    float ssum = 0.f;
    for (int r = rp; r < 256; r += 8) ssum += xk[r * 32 + c];
    red[t] = ssum;
  }
  __syncthreads();
  if (t < 32) {
    float tot = 0.f;
#pragma unroll
    for (int g = 0; g < 8; ++g) tot += red[g * 32 + t];
    cent[t] = tot * (1.f / 256.f);
  }
  __syncthreads();
  if (t < 128) {
    float s = mb1[t];
#pragma unroll
    for (int c = 0; c < 32; ++c) s += cent[c] * mw1[c * 128 + t];
    h1[t] = fmaxf(s, 0.f);
  }
  __syncthreads();
  float s = mb2[t];
  for (int j = 0; j < 128; ++j) s += h1[j] * mw2[j * 256 + t];
  h2buf[k * 256 + t] = fmaxf(s, 0.f);
}

__global__ __launch_bounds__(256) void k_mlp2(
    const float* __restrict__ h2buf,
    const float* __restrict__ mw3, const float* __restrict__ mb3,
    float* __restrict__ swb) {
  const int k = blockIdx.y, t = threadIdx.x;
  const int o = blockIdx.x * 256 + t;
  __shared__ float h2s[256];
  h2s[t] = h2buf[k * 256 + t];
  __syncthreads();
  float s = mb3[o];
  for (int j = 0; j < 256; ++j) s += h2s[j] * mw3[j * 1024 + o];
  swb[k * 1024 + o] = 1.f / (1.f + __expf(-s));
}

__global__ __launch_bounds__(256) void k_mlp3(
    const float* __restrict__ swb,
    const float* __restrict__ gcnw,
    float* __restrict__ weff) {
  const int k = blockIdx.y, t = threadIdx.x;
  const int e = blockIdx.x * 256 + t;           // 0..2047
  __shared__ float swl[1024];
#pragma unroll
  for (int j = 0; j < 4; ++j) swl[t + j * 256] = swb[k * 1024 + t + j * 256];
  __syncthreads();
  const int u = e >> 5, v = e & 31;
  const float* gk = gcnw + (size_t)k * 2048;
  float s = 0.f;
#pragma unroll
  for (int ss = 0; ss < 32; ++ss) s += gk[u * 32 + ss] * swl[ss * 32 + v];
  weff[(size_t)k * 2048 + e] = s;
}

// --------------------------- fused pair chain -------------------------------
// Swapped MFMA scheme.  Block = one 16p x 32q half-tile of an upper-tri 32x32
// tile; 4 waves, each wave: 4 p values x 2 q-groups(16q) = 8 reps.
// GEMM1:  h1^T[o][q] = mfma(A=w1 frag, B=d frag); lane(l15,lg) holds
//         q=Q0+l15, o = 16f+4lg+r   (acc1[f][r]).
// GEMM2:  B-frag built in-register from bn1(h1) values; w2 pre-permuted along
//         K so channel order matches.  Lane holds h2 at o2 = 16f2+4lg+r.
// Mode 0: BN1 stats.  Mode 1: BN2 stats.  Mode 2: logits (+mirror).
template <int MODE>
__global__ __launch_bounds__(256, (MODE == 0) ? 3 : 2) void k_conv(
    const float* __restrict__ xi,
    const unsigned short* __restrict__ w1b,
    const unsigned short* __restrict__ w2p,
    const float2* __restrict__ coef1,
    const float4* __restrict__ coefL,
    float* __restrict__ stats1,
    float* __restrict__ stats2,
    float* __restrict__ logits) {
  const int k   = blockIdx.y;
  const int t36 = blockIdx.x >> 1;
  const int ph  = blockIdx.x & 1;
  int a = 0, rem = t36;
  while (rem >= 8 - a) { rem -= 8 - a; ++a; }
  const int b = a + rem;                 // a<=b
  const float w = (a == b) ? 1.f : 2.f;

  const int tid = threadIdx.x;
  const int lane = tid & 63;
  const int wv  = tid >> 6;
  const int l15 = lane & 15;
  const int lg  = lane >> 4;

  const int Pb = a * 32 + ph * 16 + wv * 4;   // this wave's 4 p's
  const int Qb = b * 32;

  constexpr int NF  = (MODE == 0) ? 4 : 6;
  constexpr int NCH = NF * 4;                 // channels per lane for stats

  __shared__ float sred[192];
  __shared__ float4 cLs[96];

  if (tid < 192) sred[tid] = 0.f;
  if constexpr (MODE == 2) {
    if (tid < 96) cLs[tid] = coefL[k * 96 + tid];
  }

  const float* xik = xi + (size_t)k * 8192;

  float qv[2][8], pv[4][8];
#pragma unroll
  for (int qg = 0; qg < 2; ++qg) {
    const f32x4* src = (const f32x4*)(xik + (size_t)(Qb + qg * 16 + l15) * 32 + lg * 8);
    f32x4 v0 = src[0], v1 = src[1];
#pragma unroll
    for (int j = 0; j < 4; ++j) { qv[qg][j] = v0[j]; qv[qg][4 + j] = v1[j]; }
  }
#pragma unroll
  for (int pl = 0; pl < 4; ++pl) {
    const f32x4* src = (const f32x4*)(xik + (size_t)(Pb + pl) * 32 + lg * 8);
    f32x4 v0 = src[0], v1 = src[1];
#pragma unroll
    for (int j = 0; j < 4; ++j) { pv[pl][j] = v0[j]; pv[pl][4 + j] = v1[j]; }
  }

  bfrag8 B1[4];
  {
    const unsigned short* w1k = w1b + k * 2048;
#pragma unroll
    for (int f = 0; f < 4; ++f)
      B1[f] = *(const bfrag8*)(w1k + (16 * f + l15) * 32 + lg * 8);
  }
  bfrag8 B2[6][2];
  float2 c1[16];
  if constexpr (MODE >= 1) {
    const unsigned short* w2k = w2p + k * 6144;
#pragma unroll
    for (int f2 = 0; f2 < 6; ++f2) {
      B2[f2][0] = *(const bfrag8*)(w2k + (16 * f2 + l15) * 64 + lg * 8);
      B2[f2][1] = *(const bfrag8*)(w2k + (16 * f2 + l15) * 64 + 32 + lg * 8);
    }
#pragma unroll
    for (int f = 0; f < 4; ++f)
#pragma unroll
      for (int r = 0; r < 4; ++r)
        c1[f * 4 + r] = coef1[k * 64 + 16 * f + 4 * lg + r];
  }

  float ss[24], sq[24];
#pragma unroll
  for (int i = 0; i < 24; ++i) { ss[i] = 0.f; sq[i] = 0.f; }

  __syncthreads();

  const f32x4 z = {0.f, 0.f, 0.f, 0.f};
#pragma unroll
  for (int pl = 0; pl < 4; ++pl) {
    const int pglob = Pb + pl;
#pragma unroll
    for (int qg = 0; qg < 2; ++qg) {
      // d fragment (B-operand): col=q=l15, k = 8*lg+j
      bfrag8 df;
#pragma unroll
      for (int j = 0; j < 8; ++j)
        df[j] = (short)f2bf(fabsf(qv[qg][j] - pv[pl][j]));
      f32x4 acc1[4];
#pragma unroll
      for (int f = 0; f < 4; ++f)
        acc1[f] = __builtin_amdgcn_mfma_f32_16x16x32_bf16(B1[f], df, z, 0, 0, 0);

      if constexpr (MODE == 0) {
#pragma unroll
        for (int f = 0; f < 4; ++f)
#pragma unroll
          for (int r = 0; r < 4; ++r) {
            float h = acc1[f][r];
            ss[f * 4 + r] += h; sq[f * 4 + r] += h * h;
          }
      } else {
        // bn1 + lrelu, pack straight into GEMM2 B-fragments
        bfrag8 pa[2];
#pragma unroll
        for (int f = 0; f < 4; ++f)
#pragma unroll
          for (int r = 0; r < 4; ++r) {
            float h = acc1[f][r] * c1[f * 4 + r].x + c1[f * 4 + r].y;
            h = fmaxf(h, 0.2f * h);
            pa[f >> 1][(f & 1) * 4 + r] = (short)f2bf(h);
          }
        float lp = 0.f;
#pragma unroll
        for (int f2 = 0; f2 < 6; ++f2) {
          f32x4 acc = __builtin_amdgcn_mfma_f32_16x16x32_bf16(B2[f2][0], pa[0], z, 0, 0, 0);
          acc = __builtin_amdgcn_mfma_f32_16x16x32_bf16(B2[f2][1], pa[1], acc, 0, 0, 0);
          if constexpr (MODE == 1) {
#pragma unroll
            for (int r = 0; r < 4; ++r) {
              float h = acc[r];
              ss[f2 * 4 + r] += h; sq[f2 * 4 + r] += h * h;
            }
          } else {
#pragma unroll
            for (int r = 0; r < 4; ++r) {
              float4 cl = cLs[16 * f2 + 4 * lg + r];
              float aa = acc[r] * cl.x + cl.y;
              lp += 0.6f * aa + cl.z * fabsf(aa);
            }
          }
        }
        if constexpr (MODE == 2) {
          lp += __shfl_xor(lp, 16);
          lp += __shfl_xor(lp, 32);
          if (lg == 0) {
            const int q = Qb + qg * 16 + l15;
            logits[(size_t)k * 65536 + (size_t)pglob * 256 + q] = lp;
            if (a != b)
              logits[(size_t)k * 65536 + (size_t)q * 256 + pglob] = lp;
          }
        }
      }
    }
  }

  if constexpr (MODE <= 1) {
#pragma unroll
    for (int i = 0; i < NCH; ++i) {
#pragma unroll
      for (int m = 1; m <= 8; m <<= 1) {
        ss[i] += __shfl_xor(ss[i], m);
        sq[i] += __shfl_xor(sq[i], m);
      }
    }
    if (l15 == 0) {
#pragma unroll
      for (int i = 0; i < NCH; ++i) {
        int ch = 16 * (i >> 2) + 4 * lg + (i & 3);
        atomicAdd(&sred[ch * 2 + 0], ss[i] * w);
        atomicAdd(&sred[ch * 2 + 1], sq[i] * w);
      }
    }
    __syncthreads();
    float* gs = (MODE == 0) ? stats1 : stats2;
    if (tid < 2 * 16 * NF) atomicAdd(&gs[k * (2 * 16 * NF) + tid], sred[tid]);
  }
}

// ------------------------- BN coefficient kernels ---------------------------
__global__ void k_bnco1(const float* __restrict__ stats,
                        const float* __restrict__ g,
                        const float* __restrict__ b,
                        float2* __restrict__ coef) {
  int i = blockIdx.x * 256 + threadIdx.x;
  if (i >= 1024) return;                       // 16 * 64
  float sum = stats[i * 2], sqv = stats[i * 2 + 1];
  const float invN = 1.f / 65536.f;
  float mean = sum * invN;
  float var = sqv * invN - mean * mean;
  float s = g[i] * rsqrtf(fmaxf(var, 0.f) + 1e-5f);
  coef[i] = make_float2(s, b[i] - mean * s);
}

// bn2 + lrelu + conv3 dot folded: out = 0.6a + sg*|a|, a = A*h2 + B
__global__ void k_bnco2(const float* __restrict__ stats,
                        const float* __restrict__ g,
                        const float* __restrict__ b,
                        const float* __restrict__ w3,
                        float4* __restrict__ coefL) {
  int i = blockIdx.x * 256 + threadIdx.x;
  if (i >= 1536) return;                       // 16 * 96
  float sum = stats[i * 2], sqv = stats[i * 2 + 1];
  const float invN = 1.f / 65536.f;
  float mean = sum * invN;
  float var = sqv * invN - mean * mean;
  float s = g[i] * rsqrtf(fmaxf(var, 0.f) + 1e-5f);
  float t = b[i] - mean * s;
  float wv = w3[i];
  coefL[i] = make_float4(s * wv, t * wv, copysignf(0.4f, wv), 0.f);
}

// --------------------- softmax + adj@xi + GCN + BN3 stats -------------------
__global__ __launch_bounds__(256) void k_graph(
    const float* __restrict__ xi,
    const float* __restrict__ logits,
    const float* __restrict__ weff,
    float* __restrict__ hi,
    float* __restrict__ stats3) {
  const int k  = blockIdx.y;
  const int pc = blockIdx.x;   // 0..15, 16 rows each
  const int tid = threadIdx.x;
  __shared__ unsigned short xis[256 * 36];
  __shared__ float es[16][260];
  __shared__ float axs[16][34];
  __shared__ float inv_s[16];
  __shared__ float s3[64];

  const float* xik = xi + (size_t)k * 8192;
  for (int i = tid; i < 8192; i += 256) {
    int r = i >> 5, c = i & 31;
    xis[r * 36 + c] = f2bf(xik[i]);
  }
  if (tid < 64) s3[tid] = 0.f;
  __syncthreads();

  const int row = tid >> 4;    // 0..15
  const int s   = tid & 15;
  const int pglob = pc * 16 + row;
  const float* lrow = logits + (size_t)k * 65536 + (size_t)pglob * 256;

  float m = -1e30f;
  for (int q = s; q < 256; q += 16) {
    float v = lrow[q];
    m = (q == pglob) ? m : fmaxf(m, v);
  }
  m = fmaxf(m, __shfl_xor(m, 1));
  m = fmaxf(m, __shfl_xor(m, 2));
  m = fmaxf(m, __shfl_xor(m, 4));
  m = fmaxf(m, __shfl_xor(m, 8));
  float sum = 0.f;
  for (int q = s; q < 256; q += 16) {
    float e = (q == pglob) ? 0.f : __expf(lrow[q] - m);
    es[row][q] = e;
    sum += e;
  }
  sum += __shfl_xor(sum, 1);
  sum += __shfl_xor(sum, 2);
  sum += __shfl_xor(sum, 4);
  sum += __shfl_xor(sum, 8);
  if (s == 0) inv_s[row] = 1.f / sum;
  __syncthreads();

  const int c0 = s * 2;
  float a0 = 0.f, a1 = 0.f;
  for (int q = 0; q < 256; ++q) {
    float e = es[row][q];
    a0 += e * bf2f(xis[q * 36 + c0]);
    a1 += e * bf2f(xis[q * 36 + c0 + 1]);
  }
  float iv = inv_s[row];
  axs[row][c0]     = a0 * iv;
  axs[row][c0 + 1] = a1 * iv;
  __syncthreads();

  const float* wk = weff + (size_t)k * 2048;
  float h0 = 0.f, h1 = 0.f;
  for (int u = 0; u < 32; ++u) {
    float xu = bf2f(xis[pglob * 36 + u]);
    float au = axs[row][u];
    const float* w0 = wk + u * 32 + c0;
    const float* w1 = wk + (32 + u) * 32 + c0;
    h0 += xu * w0[0] + au * w1[0];
    h1 += xu * w0[1] + au * w1[1];
  }
  float v0 = fmaxf(h0, 0.2f * h0), v1 = fmaxf(h1, 0.2f * h1);
  float* hrow = hi + (size_t)k * 8192 + (size_t)pglob * 32 + c0;
  hrow[0] = v0; hrow[1] = v1;
  float vs0 = v0, vq0 = v0 * v0, vs1 = v1, vq1 = v1 * v1;
  vs0 += __shfl_xor(vs0, 16); vs0 += __shfl_xor(vs0, 32);
  vq0 += __shfl_xor(vq0, 16); vq0 += __shfl_xor(vq0, 32);
  vs1 += __shfl_xor(vs1, 16); vs1 += __shfl_xor(vs1, 32);
  vq1 += __shfl_xor(vq1, 16); vq1 += __shfl_xor(vq1, 32);
  if (((tid >> 4) & 3) == 0) {
    atomicAdd(&s3[c0 * 2 + 0], vs0);
    atomicAdd(&s3[c0 * 2 + 1], vq0);
    atomicAdd(&s3[c0 * 2 + 2], vs1);
    atomicAdd(&s3[c0 * 2 + 3], vq1);
  }
  __syncthreads();
  if (tid < 64) atomicAdd(&stats3[k * 64 + tid], s3[tid]);
}

// ------------------------------ BN3 + scatter -------------------------------
__global__ __launch_bounds__(256) void k_bn3(
    const float* __restrict__ hi, const float* __restrict__ stats3,
    const float* __restrict__ g3, const float* __restrict__ b3,
    const int* __restrict__ order, float* __restrict__ xnew) {
  int idx = blockIdx.x * 256 + threadIdx.x;   // 131072
  int k = idx >> 13, r = (idx >> 5) & 255, c = idx & 31;
  float sum = stats3[k * 64 + c * 2], sqv = stats3[k * 64 + c * 2 + 1];
  const float invN = 1.f / 256.f;
  float mean = sum * invN;
  float var = sqv * invN - mean * mean;
  float s = g3[k * 32 + c] * rsqrtf(fmaxf(var, 0.f) + 1e-5f);
  float t = b3[k * 32 + c] - mean * s;
  xnew[(size_t)order[k * 256 + r] * 32 + c] = hi[idx] * s + t;
}

// ------------------------------- final add ----------------------------------
__global__ __launch_bounds__(256) void k_final(const float* __restrict__ xc,
                                               const float* __restrict__ xnew,
                                               float* __restrict__ out) {
  int idx = blockIdx.x * 256 + threadIdx.x;   // 2097152 float4 groups
  int c4 = idx & 7, v = idx >> 3;
  int z = v & 63, y = (v >> 6) & 63, x = v >> 12;
  int sx = (x >> 2) + (x & 3) - 1;
  int sy = (y >> 2) + (y & 3) - 1;
  int sz = (z >> 2) + (z & 3) - 1;
  f32x4 add = {0.f, 0.f, 0.f, 0.f};
  if ((unsigned)sx < 16u && (unsigned)sy < 16u && (unsigned)sz < 16u)
    add = *(const f32x4*)&xnew[(size_t)(((sx << 4) + sy) * 16 + sz) * 32 + c4 * 4];
  const f32x4 a = *(const f32x4*)&xc[(size_t)idx * 4];
  *(f32x4*)&out[(size_t)idx * 4] = a + add;
}

// ----------------------------------------------------------------------------
extern "C" void kernel_launch(void* const* d_in, const int* in_sizes, int n_in,
                              void* d_out, int out_size, void* d_ws, size_t ws_size,
                              hipStream_t stream) {
  const float* xc   = (const float*)d_in[0];
  const int*   ci   = (const int*)  d_in[1];
  const float* c1w  = (const float*)d_in[2];
  const float* bn1g = (const float*)d_in[4];
  const float* bn1b = (const float*)d_in[5];
  const float* c2w  = (const float*)d_in[6];
  const float* bn2g = (const float*)d_in[8];
  const float* bn2b = (const float*)d_in[9];
  const float* c3w  = (const float*)d_in[10];
  const float* gcnw = (const float*)d_in[12];
  const float* bn3g = (const float*)d_in[13];
  const float* bn3b = (const float*)d_in[14];
  const float* mw1  = (const float*)d_in[15];
  const float* mb1  = (const float*)d_in[16];
  const float* mw2  = (const float*)d_in[17];
  const float* mb2  = (const float*)d_in[18];
  const float* mw3  = (const float*)d_in[19];
  const float* mb3  = (const float*)d_in[20];

  float* wsf = (float*)d_ws;
  float*  x      = wsf + 0;          // 131072 (dead after k_order; reused below)
  float*  xi     = wsf + 131072;     // 131072
  float*  xnew   = wsf + 262144;     // 131072
  float*  hi     = wsf + 393216;     // 131072
  float*  weff   = wsf + 524288;     // 32768
  float*  stats1 = wsf + 557056;     // 2048
  float*  stats2 = wsf + 559104;     // 3072
  float*  stats3 = wsf + 562176;     // 1024
  float2* coef1  = (float2*)(wsf + 563200);  // 2048 floats
  float4* coefL  = (float4*)(wsf + 565248);  // 6144 floats
  float*  logits = wsf + 571392;     // 1048576
  unsigned char* wsb = (unsigned char*)d_ws;
  int* order = (int*)(wsb + 6479872);
  unsigned short* w1b = (unsigned short*)(wsb + 6479872 + 16384);
  unsigned short* w2p = (unsigned short*)(wsb + 6479872 + 16384 + 65536);
  float* h2mlp = x;                  // alias dead x region
  float* swb   = x + 4096;

  hipMemsetAsync(stats1, 0, 6144 * sizeof(float), stream);  // stats1|2|3
  k_pool <<<128, 256, 0, stream>>>(xc, x);
  k_wcvt <<<384, 256, 0, stream>>>(c1w, c2w, w1b, w2p);
  k_order<<<16, 256, 0, stream>>>(ci, x, order, xi);
  k_mlp1 <<<16, 256, 0, stream>>>(xi, mw1, mb1, mw2, mb2, h2mlp);
  k_mlp2 <<<dim3(4, 16), 256, 0, stream>>>(h2mlp, mw3, mb3, swb);
  k_mlp3 <<<dim3(8, 16), 256, 0, stream>>>(swb, gcnw, weff);
  dim3 gconv(72, 16);
  k_conv<0><<<gconv, 256, 0, stream>>>(xi, w1b, w2p, coef1, coefL, stats1, stats2, logits);
  k_bnco1<<<4, 256, 0, stream>>>(stats1, bn1g, bn1b, coef1);
  k_conv<1><<<gconv, 256, 0, stream>>>(xi, w1b, w2p, coef1, coefL, stats1, stats2, logits);
  k_bnco2<<<6, 256, 0, stream>>>(stats2, bn2g, bn2b, c3w, coefL);
  k_conv<2><<<gconv, 256, 0, stream>>>(xi, w1b, w2p, coef1, coefL, stats1, stats2, logits);
  k_graph<<<dim3(16, 16), 256, 0, stream>>>(xi, logits, weff, hi, stats3);
  k_bn3  <<<512, 256, 0, stream>>>(hi, stats3, bn3g, bn3b, order, xnew);
  k_final<<<8192, 256, 0, stream>>>(xc, xnew, (float*)d_out);
}

// Round 7
// 150.688 us; speedup vs baseline: 1.1766x; 1.1218x over previous
//
#include <hip/hip_runtime.h>
#include <hip/hip_bf16.h>

// ---------------------------------------------------------------------------
// ClusterGNN fused pipeline for MI355X (gfx950).  Round 7.
//   Occupancy attack on k_conv: p-rows in LDS (broadcast), BN1 scale folded
//   into w1s, BN2*w3 scale folded into w2s, coef arrays in LDS ->
//   launch_bounds(256,3) for modes 0/2.  k_graph re-gridded 512 blocks with
//   LDS-staged weff and bf16 xi (xib written by k_order).
// ---------------------------------------------------------------------------

typedef short bfrag8 __attribute__((ext_vector_type(8)));   // 8 bf16 (4 VGPR)
typedef float f32x4  __attribute__((ext_vector_type(4)));
typedef short s4v    __attribute__((ext_vector_type(4)));

#define DI __device__ __forceinline__

DI unsigned short f2bf(float f) {
  return __builtin_bit_cast(unsigned short, __float2bfloat16(f));
}
DI float bf2f(unsigned short u) {
  return __builtin_bit_cast(float, ((unsigned)u) << 16);
}

// ------------------------------- pool --------------------------------------
__global__ __launch_bounds__(256) void k_pool(const float* __restrict__ xc,
                                              float* __restrict__ x) {
  int idx = blockIdx.x * 256 + threadIdx.x;      // 32768 = 4096*8 float4s
  int c4 = idx & 7, g = idx >> 3;
  int gz = g & 15, gy = (g >> 4) & 15, gx = g >> 8;
  f32x4 s = {0.f, 0.f, 0.f, 0.f};
  for (int ix = 0; ix < 4; ++ix)
    for (int iy = 0; iy < 4; ++iy)
      for (int iz = 0; iz < 4; ++iz) {
        int X = gx * 4 + ix, Y = gy * 4 + iy, Z = gz * 4 + iz;
        s += *(const f32x4*)&xc[(size_t)(((X << 6) | Y) << 6 | Z) * 32 + c4 * 4];
      }
  *(f32x4*)&x[(size_t)idx * 4] = s * (1.f / 64.f);
}

// --------------------------- order + gather --------------------------------
__global__ __launch_bounds__(256) void k_order(const int* __restrict__ ci,
                                               const float* __restrict__ x,
                                               int* __restrict__ order,
                                               float* __restrict__ xi,
                                               unsigned short* __restrict__ xib) {
  const int k = blockIdx.x, t = threadIdx.x;
  __shared__ int scnt[256];
  __shared__ int ordl[256];
  int match[16];
  int cnt = 0;
#pragma unroll
  for (int j = 0; j < 16; ++j) { match[j] = (ci[t * 16 + j] == k); cnt += match[j]; }
  scnt[t] = cnt;
  __syncthreads();
  for (int off = 1; off < 256; off <<= 1) {
    int v = (t >= off) ? scnt[t - off] : 0;
    __syncthreads();
    scnt[t] += v;
    __syncthreads();
  }
  int pos = scnt[t] - cnt;
#pragma unroll
  for (int j = 0; j < 16; ++j)
    if (match[j]) ordl[pos++] = t * 16 + j;
  __syncthreads();
  int src = ordl[t];
  order[k * 256 + t] = src;
  const f32x4* xr = (const f32x4*)(x + (size_t)src * 32);
  f32x4* xo = (f32x4*)(xi + ((size_t)k * 256 + t) * 32);
  uint2* xb = (uint2*)(xib + ((size_t)k * 256 + t) * 32);
#pragma unroll
  for (int c = 0; c < 8; ++c) {
    f32x4 v = xr[c];
    xo[c] = v;
    unsigned int lo = f2bf(v[0]) | ((unsigned)f2bf(v[1]) << 16);
    unsigned int hi = f2bf(v[2]) | ((unsigned)f2bf(v[3]) << 16);
    xb[c] = make_uint2(lo, hi);
  }
}

// ---------------------------- weight cvt + permute --------------------------
// w2p[o2][s*32+kp] = w2[o2][32s + 16*((kp>>2)&1) + 4*(kp>>3) + (kp&3)]
__global__ __launch_bounds__(256) void k_wcvt(const float* __restrict__ w1,
                                              const float* __restrict__ w2,
                                              unsigned short* __restrict__ w1b,
                                              unsigned short* __restrict__ w2p) {
  int i = blockIdx.x * 256 + threadIdx.x;
  if (i < 32768) w1b[i] = f2bf(w1[i]);
  if (i < 98304) {
    int o = i >> 6, cc = i & 63;
    int s = cc >> 5, kp = cc & 31;
    int src = 32 * s + 16 * ((kp >> 2) & 1) + 4 * (kp >> 3) + (kp & 3);
    w2p[i] = f2bf(w2[(size_t)o * 64 + src]);
  }
}

// ------------------------------- MLP (split) --------------------------------
__global__ __launch_bounds__(256) void k_mlp1(
    const float* __restrict__ xi,
    const float* __restrict__ mw1, const float* __restrict__ mb1,
    const float* __restrict__ mw2, const float* __restrict__ mb2,
    float* __restrict__ h2buf) {
  const int k = blockIdx.x, t = threadIdx.x;
  __shared__ float red[256];
  __shared__ float cent[32];
  __shared__ float h1[128];
  const float* xk = xi + (size_t)k * 8192;
  {
    int c = t & 31, rp = t >> 5;
    float ssum = 0.f;
    for (int r = rp; r < 256; r += 8) ssum += xk[r * 32 + c];
    red[t] = ssum;
  }
  __syncthreads();
  if (t < 32) {
    float tot = 0.f;
#pragma unroll
    for (int g = 0; g < 8; ++g) tot += red[g * 32 + t];
    cent[t] = tot * (1.f / 256.f);
  }
  __syncthreads();
  if (t < 128) {
    float s = mb1[t];
#pragma unroll
    for (int c = 0; c < 32; ++c) s += cent[c] * mw1[c * 128 + t];
    h1[t] = fmaxf(s, 0.f);
  }
  __syncthreads();
  float s = mb2[t];
  for (int j = 0; j < 128; ++j) s += h1[j] * mw2[j * 256 + t];
  h2buf[k * 256 + t] = fmaxf(s, 0.f);
}

__global__ __launch_bounds__(256) void k_mlp2(
    const float* __restrict__ h2buf,
    const float* __restrict__ mw3, const float* __restrict__ mb3,
    float* __restrict__ swb) {
  const int k = blockIdx.y, t = threadIdx.x;
  const int o = blockIdx.x * 256 + t;
  __shared__ float h2s[256];
  h2s[t] = h2buf[k * 256 + t];
  __syncthreads();
  float s = mb3[o];
  for (int j = 0; j < 256; ++j) s += h2s[j] * mw3[j * 1024 + o];
  swb[k * 1024 + o] = 1.f / (1.f + __expf(-s));
}

__global__ __launch_bounds__(256) void k_mlp3(
    const float* __restrict__ swb,
    const float* __restrict__ gcnw,
    float* __restrict__ weff) {
  const int k = blockIdx.y, t = threadIdx.x;
  const int e = blockIdx.x * 256 + t;           // 0..2047
  __shared__ float swl[1024];
#pragma unroll
  for (int j = 0; j < 4; ++j) swl[t + j * 256] = swb[k * 1024 + t + j * 256];
  __syncthreads();
  const int u = e >> 5, v = e & 31;
  const float* gk = gcnw + (size_t)k * 2048;
  float s = 0.f;
#pragma unroll
  for (int ss = 0; ss < 32; ++ss) s += gk[u * 32 + ss] * swl[ss * 32 + v];
  weff[(size_t)k * 2048 + e] = s;
}

// --------------------------- fused pair chain -------------------------------
// Swapped MFMA scheme, BN scales pre-folded into weights.
//   mode0: w1x = w1b (raw)  -> BN1 stats.
//   mode1: w1x = w1s (s-scaled), tv = coef1.y -> BN2 stats (w2x = w2p raw).
//   mode2: w1x = w1s, w2x = w2s ((s*w3)-scaled), cl2 = (B=t*w3, sg) -> logits.
template <int MODE>
__global__ __launch_bounds__(256, (MODE == 1) ? 2 : 3) void k_conv(
    const float* __restrict__ xi,
    const unsigned short* __restrict__ w1x,
    const unsigned short* __restrict__ w2x,
    const float2* __restrict__ coef1,
    const float2* __restrict__ cl2,
    float* __restrict__ stats1,
    float* __restrict__ stats2,
    float* __restrict__ logits) {
  const int k   = blockIdx.y;
  const int t36 = blockIdx.x >> 1;
  const int ph  = blockIdx.x & 1;
  int a = 0, rem = t36;
  while (rem >= 8 - a) { rem -= 8 - a; ++a; }
  const int b = a + rem;                 // a<=b
  const float w = (a == b) ? 1.f : 2.f;

  const int tid = threadIdx.x;
  const int lane = tid & 63;
  const int wv  = tid >> 6;
  const int l15 = lane & 15;
  const int lg  = lane >> 4;

  const int Pb0 = a * 32 + ph * 16;      // block's 16 p rows
  const int Qb  = b * 32;

  constexpr int NF  = (MODE == 0) ? 4 : 6;
  constexpr int NCH = NF * 4;

  __shared__ __align__(16) float xp[16][32];
  __shared__ float sred[192];
  __shared__ float2 cl2s[96];

  const float* xik = xi + (size_t)k * 8192;

  if (tid < 128) {
    int r = tid >> 3, c4 = (tid & 7) * 4;
    *(f32x4*)&xp[r][c4] = *(const f32x4*)(xik + (size_t)(Pb0 + r) * 32 + c4);
  }
  if (tid < 192) sred[tid] = 0.f;
  if constexpr (MODE == 2) {
    if (tid < 96) cl2s[tid] = cl2[k * 96 + tid];
  }

  float qv[2][8];
#pragma unroll
  for (int qg = 0; qg < 2; ++qg) {
    const f32x4* src = (const f32x4*)(xik + (size_t)(Qb + qg * 16 + l15) * 32 + lg * 8);
    f32x4 v0 = src[0], v1 = src[1];
#pragma unroll
    for (int j = 0; j < 4; ++j) { qv[qg][j] = v0[j]; qv[qg][4 + j] = v1[j]; }
  }

  bfrag8 B1[4];
  {
    const unsigned short* w1k = w1x + k * 2048;
#pragma unroll
    for (int f = 0; f < 4; ++f)
      B1[f] = *(const bfrag8*)(w1k + (16 * f + l15) * 32 + lg * 8);
  }
  bfrag8 B2[6][2];
  float tv[16];
  if constexpr (MODE >= 1) {
    const unsigned short* w2k = w2x + k * 6144;
#pragma unroll
    for (int f2 = 0; f2 < 6; ++f2) {
      B2[f2][0] = *(const bfrag8*)(w2k + (16 * f2 + l15) * 64 + lg * 8);
      B2[f2][1] = *(const bfrag8*)(w2k + (16 * f2 + l15) * 64 + 32 + lg * 8);
    }
#pragma unroll
    for (int f = 0; f < 4; ++f)
#pragma unroll
      for (int r = 0; r < 4; ++r)
        tv[f * 4 + r] = coef1[k * 64 + 16 * f + 4 * lg + r].y;
  }

  float ss[24], sq[24];
#pragma unroll
  for (int i = 0; i < 24; ++i) { ss[i] = 0.f; sq[i] = 0.f; }

  __syncthreads();

  const f32x4 z = {0.f, 0.f, 0.f, 0.f};
#pragma unroll
  for (int pl = 0; pl < 4; ++pl) {
    const int plocal = wv * 4 + pl;
    const int pglob  = Pb0 + plocal;
    const float* xpp = &xp[plocal][lg * 8];
    f32x4 p0 = *(const f32x4*)xpp;
    f32x4 p1 = *(const f32x4*)(xpp + 4);
    float pv[8];
#pragma unroll
    for (int j = 0; j < 4; ++j) { pv[j] = p0[j]; pv[4 + j] = p1[j]; }
#pragma unroll
    for (int qg = 0; qg < 2; ++qg) {
      // d fragment (B-operand): col=q=l15, k = 8*lg+j
      bfrag8 df;
#pragma unroll
      for (int j = 0; j < 8; ++j)
        df[j] = (short)f2bf(fabsf(qv[qg][j] - pv[j]));
      f32x4 acc1[4];
#pragma unroll
      for (int f = 0; f < 4; ++f)
        acc1[f] = __builtin_amdgcn_mfma_f32_16x16x32_bf16(B1[f], df, z, 0, 0, 0);

      if constexpr (MODE == 0) {
#pragma unroll
        for (int f = 0; f < 4; ++f)
#pragma unroll
          for (int r = 0; r < 4; ++r) {
            float h = acc1[f][r];
            ss[f * 4 + r] += h; sq[f * 4 + r] += h * h;
          }
      } else {
        // bn1 (scale pre-folded) + lrelu, pack into GEMM2 B-fragments
        bfrag8 pa[2];
#pragma unroll
        for (int f = 0; f < 4; ++f)
#pragma unroll
          for (int r = 0; r < 4; ++r) {
            float h = acc1[f][r] + tv[f * 4 + r];
            h = fmaxf(h, 0.2f * h);
            pa[f >> 1][(f & 1) * 4 + r] = (short)f2bf(h);
          }
        float lp = 0.f;
#pragma unroll
        for (int f2 = 0; f2 < 6; ++f2) {
          f32x4 acc = __builtin_amdgcn_mfma_f32_16x16x32_bf16(B2[f2][0], pa[0], z, 0, 0, 0);
          acc = __builtin_amdgcn_mfma_f32_16x16x32_bf16(B2[f2][1], pa[1], acc, 0, 0, 0);
          if constexpr (MODE == 1) {
#pragma unroll
            for (int r = 0; r < 4; ++r) {
              float h = acc[r];
              ss[f2 * 4 + r] += h; sq[f2 * 4 + r] += h * h;
            }
          } else {
#pragma unroll
            for (int r = 0; r < 4; ++r) {
              float2 cl = cl2s[16 * f2 + 4 * lg + r];
              float aa = acc[r] + cl.x;          // w3*(s*h2+t)
              lp = fmaf(0.6f, aa, lp);
              lp = fmaf(cl.y, fabsf(aa), lp);
            }
          }
        }
        if constexpr (MODE == 2) {
          lp += __shfl_xor(lp, 16);
          lp += __shfl_xor(lp, 32);
          if (lg == 0) {
            const int q = Qb + qg * 16 + l15;
            logits[(size_t)k * 65536 + (size_t)pglob * 256 + q] = lp;
            if (a != b)
              logits[(size_t)k * 65536 + (size_t)q * 256 + pglob] = lp;
          }
        }
      }
    }
  }

  if constexpr (MODE <= 1) {
#pragma unroll
    for (int i = 0; i < NCH; ++i) {
#pragma unroll
      for (int m = 1; m <= 8; m <<= 1) {
        ss[i] += __shfl_xor(ss[i], m);
        sq[i] += __shfl_xor(sq[i], m);
      }
    }
    if (l15 == 0) {
#pragma unroll
      for (int i = 0; i < NCH; ++i) {
        int ch = 16 * (i >> 2) + 4 * lg + (i & 3);
        atomicAdd(&sred[ch * 2 + 0], ss[i] * w);
        atomicAdd(&sred[ch * 2 + 1], sq[i] * w);
      }
    }
    __syncthreads();
    float* gs = (MODE == 0) ? stats1 : stats2;
    if (tid < 2 * 16 * NF) atomicAdd(&gs[k * (2 * 16 * NF) + tid], sred[tid]);
  }
}

// ------------------------- BN coefficient kernels ---------------------------
__global__ void k_bnco1(const float* __restrict__ stats,
                        const float* __restrict__ g,
                        const float* __restrict__ b,
                        float2* __restrict__ coef) {
  int i = blockIdx.x * 256 + threadIdx.x;
  if (i >= 1024) return;                       // 16 * 64
  float sum = stats[i * 2], sqv = stats[i * 2 + 1];
  const float invN = 1.f / 65536.f;
  float mean = sum * invN;
  float var = sqv * invN - mean * mean;
  float s = g[i] * rsqrtf(fmaxf(var, 0.f) + 1e-5f);
  coef[i] = make_float2(s, b[i] - mean * s);
}

__global__ void k_wscale1(const unsigned short* __restrict__ w1b,
                          const float2* __restrict__ coef,
                          unsigned short* __restrict__ w1s) {
  int i = blockIdx.x * 256 + threadIdx.x;      // 32768
  w1s[i] = f2bf(bf2f(w1b[i]) * coef[i >> 5].x);
}

// bn2 + lrelu + conv3 dot fold: a = (s*w3)*h2 + t*w3; out = 0.6a + sg*|a|
__global__ void k_bnco2(const float* __restrict__ stats,
                        const float* __restrict__ g,
                        const float* __restrict__ b,
                        const float* __restrict__ w3,
                        float2* __restrict__ cl2,
                        float* __restrict__ sv2) {
  int i = blockIdx.x * 256 + threadIdx.x;
  if (i >= 1536) return;                       // 16 * 96
  float sum = stats[i * 2], sqv = stats[i * 2 + 1];
  const float invN = 1.f / 65536.f;
  float mean = sum * invN;
  float var = sqv * invN - mean * mean;
  float s = g[i] * rsqrtf(fmaxf(var, 0.f) + 1e-5f);
  float t = b[i] - mean * s;
  float wv = w3[i];
  cl2[i] = make_float2(t * wv, copysignf(0.4f, wv));
  sv2[i] = s * wv;
}

__global__ void k_wscale2(const unsigned short* __restrict__ w2p,
                          const float* __restrict__ sv2,
                          unsigned short* __restrict__ w2s) {
  int i = blockIdx.x * 256 + threadIdx.x;      // 98304
  if (i < 98304) w2s[i] = f2bf(bf2f(w2p[i]) * sv2[i >> 6]);
}

// --------------------- softmax + adj@xi + GCN + BN3 stats -------------------
__global__ __launch_bounds__(256) void k_graph(
    const unsigned short* __restrict__ xib,
    const float* __restrict__ logits,
    const float* __restrict__ weff,
    float* __restrict__ hi,
    float* __restrict__ stats3) {
  const int k  = blockIdx.y;
  const int pc = blockIdx.x;   // 0..31, 8 rows each
  const int tid = threadIdx.x;
  __shared__ unsigned short xis[256 * 40];
  __shared__ float wks[2048];
  __shared__ float es[8][260];
  __shared__ float axs[8][34];
  __shared__ float inv_s[8];
  __shared__ float s3[64];

  {  // stage bf16 xi, one row per thread (pad 40 shorts)
    const s4v* src = (const s4v*)(xib + (size_t)k * 8192 + tid * 32);
    s4v* dst = (s4v*)&xis[tid * 40];
#pragma unroll
    for (int j = 0; j < 8; ++j) dst[j] = src[j];
  }
  {  // stage weff
    const float* wk = weff + (size_t)k * 2048;
#pragma unroll
    for (int j = 0; j < 8; ++j) wks[tid + j * 256] = wk[tid + j * 256];
  }
  if (tid < 64) s3[tid] = 0.f;
  __syncthreads();

  const int row = tid >> 5;    // 0..7
  const int s   = tid & 31;
  const int pglob = pc * 8 + row;
  const float* lrow = logits + (size_t)k * 65536 + (size_t)pglob * 256;

  float m = -1e30f;
  for (int q = s; q < 256; q += 32) {
    float v = lrow[q];
    m = (q == pglob) ? m : fmaxf(m, v);
  }
#pragma unroll
  for (int mm = 1; mm < 32; mm <<= 1) m = fmaxf(m, __shfl_xor(m, mm));
  float sum = 0.f;
  for (int q = s; q < 256; q += 32) {
    float e = (q == pglob) ? 0.f : __expf(lrow[q] - m);
    es[row][q] = e;
    sum += e;
  }
#pragma unroll
  for (int mm = 1; mm < 32; mm <<= 1) sum += __shfl_xor(sum, mm);
  if (s == 0) inv_s[row] = 1.f / sum;
  __syncthreads();

  float a0 = 0.f;
  for (int q = 0; q < 256; ++q)
    a0 += es[row][q] * bf2f(xis[q * 40 + s]);
  axs[row][s] = a0 * inv_s[row];
  __syncthreads();

  float h = 0.f;
  for (int u = 0; u < 32; ++u) {
    float xu = bf2f(xis[pglob * 40 + u]);
    float au = axs[row][u];
    h += xu * wks[u * 32 + s] + au * wks[(32 + u) * 32 + s];
  }
  float v = fmaxf(h, 0.2f * h);
  hi[(size_t)k * 8192 + (size_t)pglob * 32 + s] = v;
  float vs = v, vq = v * v;
  vs += __shfl_xor(vs, 32);
  vq += __shfl_xor(vq, 32);
  if ((tid & 32) == 0) {
    atomicAdd(&s3[s * 2 + 0], vs);
    atomicAdd(&s3[s * 2 + 1], vq);
  }
  __syncthreads();
  if (tid < 64) atomicAdd(&stats3[k * 64 + tid], s3[tid]);
}

// ------------------------------ BN3 + scatter -------------------------------
__global__ __launch_bounds__(256) void k_bn3(
    const float* __restrict__ hi, const float* __restrict__ stats3,
    const float* __restrict__ g3, const float* __restrict__ b3,
    const int* __restrict__ order, float* __restrict__ xnew) {
  int idx = blockIdx.x * 256 + threadIdx.x;   // 131072
  int k = idx >> 13, r = (idx >> 5) & 255, c = idx & 31;
  float sum = stats3[k * 64 + c * 2], sqv = stats3[k * 64 + c * 2 + 1];
  const float invN = 1.f / 256.f;
  float mean = sum * invN;
  float var = sqv * invN - mean * mean;
  float s = g3[k * 32 + c] * rsqrtf(fmaxf(var, 0.f) + 1e-5f);
  float t = b3[k * 32 + c] - mean * s;
  xnew[(size_t)order[k * 256 + r] * 32 + c] = hi[idx] * s + t;
}

// ------------------------------- final add ----------------------------------
__global__ __launch_bounds__(256) void k_final(const float* __restrict__ xc,
                                               const float* __restrict__ xnew,
                                               float* __restrict__ out) {
  int idx = blockIdx.x * 256 + threadIdx.x;   // 2097152 float4 groups
  int c4 = idx & 7, v = idx >> 3;
  int z = v & 63, y = (v >> 6) & 63, x = v >> 12;
  int sx = (x >> 2) + (x & 3) - 1;
  int sy = (y >> 2) + (y & 3) - 1;
  int sz = (z >> 2) + (z & 3) - 1;
  f32x4 add = {0.f, 0.f, 0.f, 0.f};
  if ((unsigned)sx < 16u && (unsigned)sy < 16u && (unsigned)sz < 16u)
    add = *(const f32x4*)&xnew[(size_t)(((sx << 4) + sy) * 16 + sz) * 32 + c4 * 4];
  const f32x4 a = *(const f32x4*)&xc[(size_t)idx * 4];
  *(f32x4*)&out[(size_t)idx * 4] = a + add;
}

// ----------------------------------------------------------------------------
extern "C" void kernel_launch(void* const* d_in, const int* in_sizes, int n_in,
                              void* d_out, int out_size, void* d_ws, size_t ws_size,
                              hipStream_t stream) {
  const float* xc   = (const float*)d_in[0];
  const int*   ci   = (const int*)  d_in[1];
  const float* c1w  = (const float*)d_in[2];
  const float* bn1g = (const float*)d_in[4];
  const float* bn1b = (const float*)d_in[5];
  const float* c2w  = (const float*)d_in[6];
  const float* bn2g = (const float*)d_in[8];
  const float* bn2b = (const float*)d_in[9];
  const float* c3w  = (const float*)d_in[10];
  const float* gcnw = (const float*)d_in[12];
  const float* bn3g = (const float*)d_in[13];
  const float* bn3b = (const float*)d_in[14];
  const float* mw1  = (const float*)d_in[15];
  const float* mb1  = (const float*)d_in[16];
  const float* mw2  = (const float*)d_in[17];
  const float* mb2  = (const float*)d_in[18];
  const float* mw3  = (const float*)d_in[19];
  const float* mb3  = (const float*)d_in[20];

  float* wsf = (float*)d_ws;
  float*  x      = wsf + 0;          // 131072 (dead after k_order; reused)
  float*  xi     = wsf + 131072;     // 131072
  float*  xnew   = wsf + 262144;     // 131072
  float*  hi     = wsf + 393216;     // 131072
  float*  weff   = wsf + 524288;     // 32768
  float*  stats1 = wsf + 557056;     // 2048
  float*  stats2 = wsf + 559104;     // 3072
  float*  stats3 = wsf + 562176;     // 1024
  float2* coef1  = (float2*)(wsf + 563200);  // 2048 floats
  float2* cl2    = (float2*)(wsf + 565248);  // 3072 floats
  float*  sv2    = wsf + 568320;     // 1536
  float*  logits = wsf + 569856;     // 1048576
  unsigned char* wsb = (unsigned char*)d_ws;
  int* order = (int*)(wsb + 6473728);
  unsigned short* w1b = (unsigned short*)(wsb + 6473728 + 16384);
  unsigned short* w2p = (unsigned short*)(wsb + 6473728 + 16384 + 65536);
  unsigned short* w1s = (unsigned short*)(wsb + 6473728 + 16384 + 65536 + 196608);
  unsigned short* w2s = (unsigned short*)(wsb + 6473728 + 16384 + 65536 + 196608 + 65536);
  unsigned short* xib = (unsigned short*)(wsb + 6473728 + 16384 + 65536 + 196608 + 65536 + 196608);
  float* h2mlp = x;                  // alias dead x region
  float* swb   = x + 4096;

  hipMemsetAsync(stats1, 0, 6144 * sizeof(float), stream);  // stats1|2|3
  k_pool <<<128, 256, 0, stream>>>(xc, x);
  k_wcvt <<<384, 256, 0, stream>>>(c1w, c2w, w1b, w2p);
  k_order<<<16, 256, 0, stream>>>(ci, x, order, xi, xib);
  k_mlp1 <<<16, 256, 0, stream>>>(xi, mw1, mb1, mw2, mb2, h2mlp);
  k_mlp2 <<<dim3(4, 16), 256, 0, stream>>>(h2mlp, mw3, mb3, swb);
  k_mlp3 <<<dim3(8, 16), 256, 0, stream>>>(swb, gcnw, weff);
  dim3 gconv(72, 16);
  k_conv<0><<<gconv, 256, 0, stream>>>(xi, w1b, w2p, coef1, cl2, stats1, stats2, logits);
  k_bnco1<<<4, 256, 0, stream>>>(stats1, bn1g, bn1b, coef1);
  k_wscale1<<<128, 256, 0, stream>>>(w1b, coef1, w1s);
  k_conv<1><<<gconv, 256, 0, stream>>>(xi, w1s, w2p, coef1, cl2, stats1, stats2, logits);
  k_bnco2<<<6, 256, 0, stream>>>(stats2, bn2g, bn2b, c3w, cl2, sv2);
  k_wscale2<<<384, 256, 0, stream>>>(w2p, sv2, w2s);
  k_conv<2><<<gconv, 256, 0, stream>>>(xi, w1s, w2s, coef1, cl2, stats1, stats2, logits);
  k_graph<<<dim3(32, 16), 256, 0, stream>>>(xib, logits, weff, hi, stats3);
  k_bn3  <<<512, 256, 0, stream>>>(hi, stats3, bn3g, bn3b, order, xnew);
  k_final<<<8192, 256, 0, stream>>>(xc, xnew, (float*)d_out);
}

// Round 8
// 139.599 us; speedup vs baseline: 1.2700x; 1.0794x over previous
//
#include <hip/hip_runtime.h>
#include <hip/hip_bf16.h>

// ---------------------------------------------------------------------------
// ClusterGNN fused pipeline for MI355X (gfx950).  Round 8.
//   k_conv VALU diet: v_perm bf16 packing (round-half-up), BN biases moved
//   into MFMA C-operand (LDS f32x4 reads), 3-inst epilogue per channel.
//   BN1/BN2 stats passes sample every-other p row (N=32768, unbiased).
//   s_setprio(1) around MFMA clusters.  bnco kernels folded into wscale.
// ---------------------------------------------------------------------------

typedef short bfrag8 __attribute__((ext_vector_type(8)));   // 8 bf16 (4 VGPR)
typedef float f32x4  __attribute__((ext_vector_type(4)));
typedef int   i32x4  __attribute__((ext_vector_type(4)));
typedef short s4v    __attribute__((ext_vector_type(4)));

#define DI __device__ __forceinline__

DI unsigned short f2bf(float f) {
  return __builtin_bit_cast(unsigned short, __float2bfloat16(f));
}
DI float bf2f(unsigned short u) {
  return __builtin_bit_cast(float, ((unsigned)u) << 16);
}
// pack two floats to two bf16 (round-half-up) in one u32: lo in [0:16), hi in [16:32)
DI unsigned pack2bf(float lo, float hi) {
  unsigned ulo = __builtin_bit_cast(unsigned, lo) + 0x8000u;
  unsigned uhi = __builtin_bit_cast(unsigned, hi) + 0x8000u;
  return __builtin_amdgcn_perm(uhi, ulo, 0x07060302u);
}

// ------------------------------- pool --------------------------------------
__global__ __launch_bounds__(256) void k_pool(const float* __restrict__ xc,
                                              float* __restrict__ x) {
  int idx = blockIdx.x * 256 + threadIdx.x;      // 32768 = 4096*8 float4s
  int c4 = idx & 7, g = idx >> 3;
  int gz = g & 15, gy = (g >> 4) & 15, gx = g >> 8;
  f32x4 s = {0.f, 0.f, 0.f, 0.f};
  for (int ix = 0; ix < 4; ++ix)
    for (int iy = 0; iy < 4; ++iy)
      for (int iz = 0; iz < 4; ++iz) {
        int X = gx * 4 + ix, Y = gy * 4 + iy, Z = gz * 4 + iz;
        s += *(const f32x4*)&xc[(size_t)(((X << 6) | Y) << 6 | Z) * 32 + c4 * 4];
      }
  *(f32x4*)&x[(size_t)idx * 4] = s * (1.f / 64.f);
}

// --------------------------- order + gather --------------------------------
__global__ __launch_bounds__(256) void k_order(const int* __restrict__ ci,
                                               const float* __restrict__ x,
                                               int* __restrict__ order,
                                               float* __restrict__ xi,
                                               unsigned short* __restrict__ xib) {
  const int k = blockIdx.x, t = threadIdx.x;
  __shared__ int scnt[256];
  __shared__ int ordl[256];
  int match[16];
  int cnt = 0;
#pragma unroll
  for (int j = 0; j < 16; ++j) { match[j] = (ci[t * 16 + j] == k); cnt += match[j]; }
  scnt[t] = cnt;
  __syncthreads();
  for (int off = 1; off < 256; off <<= 1) {
    int v = (t >= off) ? scnt[t - off] : 0;
    __syncthreads();
    scnt[t] += v;
    __syncthreads();
  }
  int pos = scnt[t] - cnt;
#pragma unroll
  for (int j = 0; j < 16; ++j)
    if (match[j]) ordl[pos++] = t * 16 + j;
  __syncthreads();
  int src = ordl[t];
  order[k * 256 + t] = src;
  const f32x4* xr = (const f32x4*)(x + (size_t)src * 32);
  f32x4* xo = (f32x4*)(xi + ((size_t)k * 256 + t) * 32);
  uint2* xb = (uint2*)(xib + ((size_t)k * 256 + t) * 32);
#pragma unroll
  for (int c = 0; c < 8; ++c) {
    f32x4 v = xr[c];
    xo[c] = v;
    unsigned int lo = f2bf(v[0]) | ((unsigned)f2bf(v[1]) << 16);
    unsigned int hi = f2bf(v[2]) | ((unsigned)f2bf(v[3]) << 16);
    xb[c] = make_uint2(lo, hi);
  }
}

// ---------------------------- weight cvt + permute --------------------------
// w2p[o2][s*32+kp] = w2[o2][32s + 16*((kp>>2)&1) + 4*(kp>>3) + (kp&3)]
__global__ __launch_bounds__(256) void k_wcvt(const float* __restrict__ w1,
                                              const float* __restrict__ w2,
                                              unsigned short* __restrict__ w1b,
                                              unsigned short* __restrict__ w2p) {
  int i = blockIdx.x * 256 + threadIdx.x;
  if (i < 32768) w1b[i] = f2bf(w1[i]);
  if (i < 98304) {
    int o = i >> 6, cc = i & 63;
    int s = cc >> 5, kp = cc & 31;
    int src = 32 * s + 16 * ((kp >> 2) & 1) + 4 * (kp >> 3) + (kp & 3);
    w2p[i] = f2bf(w2[(size_t)o * 64 + src]);
  }
}

// ------------------------------- MLP (split) --------------------------------
__global__ __launch_bounds__(256) void k_mlp1(
    const float* __restrict__ xi,
    const float* __restrict__ mw1, const float* __restrict__ mb1,
    const float* __restrict__ mw2, const float* __restrict__ mb2,
    float* __restrict__ h2buf) {
  const int k = blockIdx.x, t = threadIdx.x;
  __shared__ float red[256];
  __shared__ float cent[32];
  __shared__ float h1[128];
  const float* xk = xi + (size_t)k * 8192;
  {
    int c = t & 31, rp = t >> 5;
    float ssum = 0.f;
    for (int r = rp; r < 256; r += 8) ssum += xk[r * 32 + c];
    red[t] = ssum;
  }
  __syncthreads();
  if (t < 32) {
    float tot = 0.f;
#pragma unroll
    for (int g = 0; g < 8; ++g) tot += red[g * 32 + t];
    cent[t] = tot * (1.f / 256.f);
  }
  __syncthreads();
  if (t < 128) {
    float s = mb1[t];
#pragma unroll
    for (int c = 0; c < 32; ++c) s += cent[c] * mw1[c * 128 + t];
    h1[t] = fmaxf(s, 0.f);
  }
  __syncthreads();
  float s = mb2[t];
  for (int j = 0; j < 128; ++j) s += h1[j] * mw2[j * 256 + t];
  h2buf[k * 256 + t] = fmaxf(s, 0.f);
}

__global__ __launch_bounds__(256) void k_mlp2(
    const float* __restrict__ h2buf,
    const float* __restrict__ mw3, const float* __restrict__ mb3,
    float* __restrict__ swb) {
  const int k = blockIdx.y, t = threadIdx.x;
  const int o = blockIdx.x * 256 + t;
  __shared__ float h2s[256];
  h2s[t] = h2buf[k * 256 + t];
  __syncthreads();
  float s = mb3[o];
  for (int j = 0; j < 256; ++j) s += h2s[j] * mw3[j * 1024 + o];
  swb[k * 1024 + o] = 1.f / (1.f + __expf(-s));
}

__global__ __launch_bounds__(256) void k_mlp3(
    const float* __restrict__ swb,
    const float* __restrict__ gcnw,
    float* __restrict__ weff) {
  const int k = blockIdx.y, t = threadIdx.x;
  const int e = blockIdx.x * 256 + t;           // 0..2047
  __shared__ float swl[1024];
#pragma unroll
  for (int j = 0; j < 4; ++j) swl[t + j * 256] = swb[k * 1024 + t + j * 256];
  __syncthreads();
  const int u = e >> 5, v = e & 31;
  const float* gk = gcnw + (size_t)k * 2048;
  float s = 0.f;
#pragma unroll
  for (int ss = 0; ss < 32; ++ss) s += gk[u * 32 + ss] * swl[ss * 32 + v];
  weff[(size_t)k * 2048 + e] = s;
}

// --------------------------- fused pair chain -------------------------------
// Swapped MFMA, BN scales folded into weights, BN biases via MFMA C-operand.
//   mode0: raw w1b, C=0 -> BN1 stats (sampled p%4 in {0,2}).
//   mode1: w1s + t1 C-in -> a1; raw w2p, C=0 -> BN2 stats (sampled).
//   mode2: w1s + t1 C-in; w2s(s*w3-scaled) + cb2(t*w3) C-in ->
//          lp += 0.6*aa + s42*|aa|; full pairs, mirror-write logits.
template <int MODE>
__global__ __launch_bounds__(256, (MODE == 0) ? 4 : ((MODE == 1) ? 2 : 3)) void k_conv(
    const float* __restrict__ xi,
    const unsigned short* __restrict__ w1x,
    const unsigned short* __restrict__ w2x,
    const float* __restrict__ t1,
    const float* __restrict__ cb2,
    const float* __restrict__ s42,
    float* __restrict__ stats1,
    float* __restrict__ stats2,
    float* __restrict__ logits) {
  const int k   = blockIdx.y;
  const int t36 = blockIdx.x >> 1;
  const int ph  = blockIdx.x & 1;
  int a = 0, rem = t36;
  while (rem >= 8 - a) { rem -= 8 - a; ++a; }
  const int b = a + rem;                 // a<=b
  const float w = (a == b) ? 1.f : 2.f;

  const int tid = threadIdx.x;
  const int lane = tid & 63;
  const int wv  = tid >> 6;
  const int l15 = lane & 15;
  const int lg  = lane >> 4;

  const int Pb0 = a * 32 + ph * 16;      // block's 16 p rows
  const int Qb  = b * 32;

  constexpr int NF  = (MODE == 0) ? 4 : 6;
  constexpr int NCH = NF * 4;
  constexpr int PLN  = (MODE == 2) ? 4 : 2;   // sampled p's per wave
  constexpr int STEP = (MODE == 2) ? 1 : 2;

  __shared__ __align__(16) float xp[16][32];
  __shared__ float sred[192];
  __shared__ __align__(16) float t1s[64];
  __shared__ __align__(16) float cb2s[96];
  __shared__ __align__(16) float s42s[96];

  const float* xik = xi + (size_t)k * 8192;

  if (tid < 128) {
    int r = tid >> 3, c4 = (tid & 7) * 4;
    *(f32x4*)&xp[r][c4] = *(const f32x4*)(xik + (size_t)(Pb0 + r) * 32 + c4);
  }
  if constexpr (MODE <= 1) {
    if (tid < 192) sred[tid] = 0.f;
  }
  if constexpr (MODE >= 1) {
    if (tid >= 192 && tid < 256) t1s[tid - 192] = t1[k * 64 + tid - 192];
  }
  if constexpr (MODE == 2) {
    if (tid < 96) cb2s[tid] = cb2[k * 96 + tid];
    else if (tid >= 96 && tid < 192) s42s[tid - 96] = s42[k * 96 + tid - 96];
  }

  float qv[2][8];
#pragma unroll
  for (int qg = 0; qg < 2; ++qg) {
    const f32x4* src = (const f32x4*)(xik + (size_t)(Qb + qg * 16 + l15) * 32 + lg * 8);
    f32x4 v0 = src[0], v1 = src[1];
#pragma unroll
    for (int j = 0; j < 4; ++j) { qv[qg][j] = v0[j]; qv[qg][4 + j] = v1[j]; }
  }

  bfrag8 B1[4];
  {
    const unsigned short* w1k = w1x + k * 2048;
#pragma unroll
    for (int f = 0; f < 4; ++f)
      B1[f] = *(const bfrag8*)(w1k + (16 * f + l15) * 32 + lg * 8);
  }
  bfrag8 B2[6][2];
  if constexpr (MODE >= 1) {
    const unsigned short* w2k = w2x + k * 6144;
#pragma unroll
    for (int f2 = 0; f2 < 6; ++f2) {
      B2[f2][0] = *(const bfrag8*)(w2k + (16 * f2 + l15) * 64 + lg * 8);
      B2[f2][1] = *(const bfrag8*)(w2k + (16 * f2 + l15) * 64 + 32 + lg * 8);
    }
  }

  float ss[24], sq[24];
#pragma unroll
  for (int i = 0; i < 24; ++i) { ss[i] = 0.f; sq[i] = 0.f; }

  __syncthreads();

  const f32x4 z = {0.f, 0.f, 0.f, 0.f};
#pragma unroll
  for (int pl = 0; pl < PLN; ++pl) {
    const int plocal = wv * 4 + pl * STEP;
    const int pglob  = Pb0 + plocal;
    const float* xpp = &xp[plocal][lg * 8];
    f32x4 p0 = *(const f32x4*)xpp;
    f32x4 p1 = *(const f32x4*)(xpp + 4);
    float pv[8];
#pragma unroll
    for (int j = 0; j < 4; ++j) { pv[j] = p0[j]; pv[4 + j] = p1[j]; }
#pragma unroll
    for (int qg = 0; qg < 2; ++qg) {
      // d fragment: col=q=l15, k = 8*lg+j ; packed via v_perm
      unsigned dw[4];
#pragma unroll
      for (int wj = 0; wj < 4; ++wj) {
        float d0 = fabsf(qv[qg][2 * wj]     - pv[2 * wj]);
        float d1 = fabsf(qv[qg][2 * wj + 1] - pv[2 * wj + 1]);
        dw[wj] = pack2bf(d0, d1);
      }
      i32x4 dwi = {(int)dw[0], (int)dw[1], (int)dw[2], (int)dw[3]};
      bfrag8 df = __builtin_bit_cast(bfrag8, dwi);

      f32x4 acc1[4];
      __builtin_amdgcn_s_setprio(1);
#pragma unroll
      for (int f = 0; f < 4; ++f) {
        f32x4 cin;
        if constexpr (MODE == 0) cin = z;
        else cin = *(const f32x4*)&t1s[16 * f + 4 * lg];
        acc1[f] = __builtin_amdgcn_mfma_f32_16x16x32_bf16(B1[f], df, cin, 0, 0, 0);
      }
      __builtin_amdgcn_s_setprio(0);

      if constexpr (MODE == 0) {
#pragma unroll
        for (int f = 0; f < 4; ++f)
#pragma unroll
          for (int r = 0; r < 4; ++r) {
            float h = acc1[f][r];
            ss[f * 4 + r] += h; sq[f * 4 + r] = fmaf(h, h, sq[f * 4 + r]);
          }
      } else {
        // a1 = lrelu(acc1) packed into GEMM2 B-fragments via v_perm
        unsigned paw[8];
#pragma unroll
        for (int f = 0; f < 4; ++f) {
          float h0 = acc1[f][0], h1 = acc1[f][1], h2 = acc1[f][2], h3 = acc1[f][3];
          h0 = fmaxf(h0, 0.2f * h0); h1 = fmaxf(h1, 0.2f * h1);
          h2 = fmaxf(h2, 0.2f * h2); h3 = fmaxf(h3, 0.2f * h3);
          paw[f * 2]     = pack2bf(h0, h1);
          paw[f * 2 + 1] = pack2bf(h2, h3);
        }
        i32x4 pa0i = {(int)paw[0], (int)paw[1], (int)paw[2], (int)paw[3]};
        i32x4 pa1i = {(int)paw[4], (int)paw[5], (int)paw[6], (int)paw[7]};
        bfrag8 pa0 = __builtin_bit_cast(bfrag8, pa0i);
        bfrag8 pa1 = __builtin_bit_cast(bfrag8, pa1i);

        float lp = 0.f;
        __builtin_amdgcn_s_setprio(1);
#pragma unroll
        for (int f2 = 0; f2 < 6; ++f2) {
          f32x4 cin;
          if constexpr (MODE == 2) cin = *(const f32x4*)&cb2s[16 * f2 + 4 * lg];
          else cin = z;
          f32x4 acc = __builtin_amdgcn_mfma_f32_16x16x32_bf16(B2[f2][0], pa0, cin, 0, 0, 0);
          acc = __builtin_amdgcn_mfma_f32_16x16x32_bf16(B2[f2][1], pa1, acc, 0, 0, 0);
          if constexpr (MODE == 1) {
#pragma unroll
            for (int r = 0; r < 4; ++r) {
              float h = acc[r];
              ss[f2 * 4 + r] += h; sq[f2 * 4 + r] = fmaf(h, h, sq[f2 * 4 + r]);
            }
          } else {
            f32x4 s4 = *(const f32x4*)&s42s[16 * f2 + 4 * lg];
#pragma unroll
            for (int r = 0; r < 4; ++r) {
              float aa = acc[r];
              float ab = fmaxf(aa, -aa);
              lp = fmaf(0.6f, aa, lp);
              lp = fmaf(s4[r], ab, lp);
            }
          }
        }
        __builtin_amdgcn_s_setprio(0);
        if constexpr (MODE == 2) {
          lp += __shfl_xor(lp, 16);
          lp += __shfl_xor(lp, 32);
          if (lg == 0) {
            const int q = Qb + qg * 16 + l15;
            logits[(size_t)k * 65536 + (size_t)pglob * 256 + q] = lp;
            if (a != b)
              logits[(size_t)k * 65536 + (size_t)q * 256 + pglob] = lp;
          }
        }
      }
    }
  }

  if constexpr (MODE <= 1) {
#pragma unroll
    for (int i = 0; i < NCH; ++i) {
#pragma unroll
      for (int m = 1; m <= 8; m <<= 1) {
        ss[i] += __shfl_xor(ss[i], m);
        sq[i] += __shfl_xor(sq[i], m);
      }
    }
    if (l15 == 0) {
#pragma unroll
      for (int i = 0; i < NCH; ++i) {
        int ch = 16 * (i >> 2) + 4 * lg + (i & 3);
        atomicAdd(&sred[ch * 2 + 0], ss[i] * w);
        atomicAdd(&sred[ch * 2 + 1], sq[i] * w);
      }
    }
    __syncthreads();
    float* gs = (MODE == 0) ? stats1 : stats2;
    if (tid < 2 * 16 * NF) atomicAdd(&gs[k * (2 * 16 * NF) + tid], sred[tid]);
  }
}

// ---------------- BN coef + weight-scale (merged) ---------------------------
// sampled N = 32768 pairs
__global__ __launch_bounds__(256) void k_wsc1(
    const float* __restrict__ stats, const float* __restrict__ g,
    const float* __restrict__ b, const unsigned short* __restrict__ w1b,
    unsigned short* __restrict__ w1s, float* __restrict__ t1) {
  int i = blockIdx.x * 256 + threadIdx.x;      // 32768
  int ch = i >> 5;
  float sum = stats[ch * 2], sqv = stats[ch * 2 + 1];
  const float invN = 1.f / 32768.f;
  float mean = sum * invN;
  float var = sqv * invN - mean * mean;
  float s = g[ch] * rsqrtf(fmaxf(var, 0.f) + 1e-5f);
  w1s[i] = f2bf(bf2f(w1b[i]) * s);
  if ((i & 31) == 0) t1[ch] = b[ch] - mean * s;
}

__global__ __launch_bounds__(256) void k_wsc2(
    const float* __restrict__ stats, const float* __restrict__ g,
    const float* __restrict__ b, const float* __restrict__ w3,
    const unsigned short* __restrict__ w2p,
    unsigned short* __restrict__ w2s,
    float* __restrict__ cb2, float* __restrict__ s42) {
  int i = blockIdx.x * 256 + threadIdx.x;      // 98304
  if (i >= 98304) return;
  int o = i >> 6;
  float sum = stats[o * 2], sqv = stats[o * 2 + 1];
  const float invN = 1.f / 32768.f;
  float mean = sum * invN;
  float var = sqv * invN - mean * mean;
  float s = g[o] * rsqrtf(fmaxf(var, 0.f) + 1e-5f);
  float t = b[o] - mean * s;
  float wv = w3[o];
  w2s[i] = f2bf(bf2f(w2p[i]) * (s * wv));
  if ((i & 63) == 0) {
    cb2[o] = t * wv;
    s42[o] = copysignf(0.4f, wv);
  }
}

// --------------------- softmax + adj@xi + GCN + BN3 stats -------------------
__global__ __launch_bounds__(256) void k_graph(
    const unsigned short* __restrict__ xib,
    const float* __restrict__ logits,
    const float* __restrict__ weff,
    float* __restrict__ hi,
    float* __restrict__ stats3) {
  const int k  = blockIdx.y;
  const int pc = blockIdx.x;   // 0..31, 8 rows each
  const int tid = threadIdx.x;
  __shared__ unsigned short xis[256 * 40];
  __shared__ float wks[2048];
  __shared__ float es[8][260];
  __shared__ float axs[8][34];
  __shared__ float inv_s[8];
  __shared__ float s3[64];

  {  // stage bf16 xi, one row per thread (pad 40 shorts)
    const s4v* src = (const s4v*)(xib + (size_t)k * 8192 + tid * 32);
    s4v* dst = (s4v*)&xis[tid * 40];
#pragma unroll
    for (int j = 0; j < 8; ++j) dst[j] = src[j];
  }
  {  // stage weff
    const float* wk = weff + (size_t)k * 2048;
#pragma unroll
    for (int j = 0; j < 8; ++j) wks[tid + j * 256] = wk[tid + j * 256];
  }
  if (tid < 64) s3[tid] = 0.f;
  __syncthreads();

  const int row = tid >> 5;    // 0..7
  const int s   = tid & 31;
  const int pglob = pc * 8 + row;
  const float* lrow = logits + (size_t)k * 65536 + (size_t)pglob * 256;

  float m = -1e30f;
  for (int q = s; q < 256; q += 32) {
    float v = lrow[q];
    m = (q == pglob) ? m : fmaxf(m, v);
  }
#pragma unroll
  for (int mm = 1; mm < 32; mm <<= 1) m = fmaxf(m, __shfl_xor(m, mm));
  float sum = 0.f;
  for (int q = s; q < 256; q += 32) {
    float e = (q == pglob) ? 0.f : __expf(lrow[q] - m);
    es[row][q] = e;
    sum += e;
  }
#pragma unroll
  for (int mm = 1; mm < 32; mm <<= 1) sum += __shfl_xor(sum, mm);
  if (s == 0) inv_s[row] = 1.f / sum;
  __syncthreads();

  float a0 = 0.f;
  for (int q = 0; q < 256; ++q)
    a0 += es[row][q] * bf2f(xis[q * 40 + s]);
  axs[row][s] = a0 * inv_s[row];
  __syncthreads();

  float h = 0.f;
  for (int u = 0; u < 32; ++u) {
    float xu = bf2f(xis[pglob * 40 + u]);
    float au = axs[row][u];
    h += xu * wks[u * 32 + s] + au * wks[(32 + u) * 32 + s];
  }
  float v = fmaxf(h, 0.2f * h);
  hi[(size_t)k * 8192 + (size_t)pglob * 32 + s] = v;
  float vs = v, vq = v * v;
  vs += __shfl_xor(vs, 32);
  vq += __shfl_xor(vq, 32);
  if ((tid & 32) == 0) {
    atomicAdd(&s3[s * 2 + 0], vs);
    atomicAdd(&s3[s * 2 + 1], vq);
  }
  __syncthreads();
  if (tid < 64) atomicAdd(&stats3[k * 64 + tid], s3[tid]);
}

// ------------------------------ BN3 + scatter -------------------------------
__global__ __launch_bounds__(256) void k_bn3(
    const float* __restrict__ hi, const float* __restrict__ stats3,
    const float* __restrict__ g3, const float* __restrict__ b3,
    const int* __restrict__ order, float* __restrict__ xnew) {
  int idx = blockIdx.x * 256 + threadIdx.x;   // 131072
  int k = idx >> 13, r = (idx >> 5) & 255, c = idx & 31;
  float sum = stats3[k * 64 + c * 2], sqv = stats3[k * 64 + c * 2 + 1];
  const float invN = 1.f / 256.f;
  float mean = sum * invN;
  float var = sqv * invN - mean * mean;
  float s = g3[k * 32 + c] * rsqrtf(fmaxf(var, 0.f) + 1e-5f);
  float t = b3[k * 32 + c] - mean * s;
  xnew[(size_t)order[k * 256 + r] * 32 + c] = hi[idx] * s + t;
}

// ------------------------------- final add ----------------------------------
__global__ __launch_bounds__(256) void k_final(const float* __restrict__ xc,
                                               const float* __restrict__ xnew,
                                               float* __restrict__ out) {
  int idx = blockIdx.x * 256 + threadIdx.x;   // 2097152 float4 groups
  int c4 = idx & 7, v = idx >> 3;
  int z = v & 63, y = (v >> 6) & 63, x = v >> 12;
  int sx = (x >> 2) + (x & 3) - 1;
  int sy = (y >> 2) + (y & 3) - 1;
  int sz = (z >> 2) + (z & 3) - 1;
  f32x4 add = {0.f, 0.f, 0.f, 0.f};
  if ((unsigned)sx < 16u && (unsigned)sy < 16u && (unsigned)sz < 16u)
    add = *(const f32x4*)&xnew[(size_t)(((sx << 4) + sy) * 16 + sz) * 32 + c4 * 4];
  const f32x4 a = *(const f32x4*)&xc[(size_t)idx * 4];
  *(f32x4*)&out[(size_t)idx * 4] = a + add;
}

// ----------------------------------------------------------------------------
extern "C" void kernel_launch(void* const* d_in, const int* in_sizes, int n_in,
                              void* d_out, int out_size, void* d_ws, size_t ws_size,
                              hipStream_t stream) {
  const float* xc   = (const float*)d_in[0];
  const int*   ci   = (const int*)  d_in[1];
  const float* c1w  = (const float*)d_in[2];
  const float* bn1g = (const float*)d_in[4];
  const float* bn1b = (const float*)d_in[5];
  const float* c2w  = (const float*)d_in[6];
  const float* bn2g = (const float*)d_in[8];
  const float* bn2b = (const float*)d_in[9];
  const float* c3w  = (const float*)d_in[10];
  const float* gcnw = (const float*)d_in[12];
  const float* bn3g = (const float*)d_in[13];
  const float* bn3b = (const float*)d_in[14];
  const float* mw1  = (const float*)d_in[15];
  const float* mb1  = (const float*)d_in[16];
  const float* mw2  = (const float*)d_in[17];
  const float* mb2  = (const float*)d_in[18];
  const float* mw3  = (const float*)d_in[19];
  const float* mb3  = (const float*)d_in[20];

  float* wsf = (float*)d_ws;
  float*  x      = wsf + 0;          // 131072 (dead after k_order; reused)
  float*  xi     = wsf + 131072;     // 131072
  float*  xnew   = wsf + 262144;     // 131072
  float*  hi     = wsf + 393216;     // 131072
  float*  weff   = wsf + 524288;     // 32768
  float*  stats1 = wsf + 557056;     // 2048
  float*  stats2 = wsf + 559104;     // 3072
  float*  stats3 = wsf + 562176;     // 1024
  float*  t1     = wsf + 563200;     // 1024
  float*  cb2    = wsf + 564224;     // 1536
  float*  s42    = wsf + 565760;     // 1536
  float*  logits = wsf + 567296;     // 1048576
  unsigned char* wsb = (unsigned char*)d_ws;
  int* order = (int*)(wsb + 6463488);
  unsigned short* w1b = (unsigned short*)(wsb + 6463488 + 16384);
  unsigned short* w2p = (unsigned short*)(wsb + 6463488 + 16384 + 65536);
  unsigned short* w1s = (unsigned short*)(wsb + 6463488 + 16384 + 65536 + 196608);
  unsigned short* w2s = (unsigned short*)(wsb + 6463488 + 16384 + 65536 + 196608 + 65536);
  unsigned short* xib = (unsigned short*)(wsb + 6463488 + 16384 + 65536 + 196608 + 65536 + 196608);
  float* h2mlp = x;                  // alias dead x region
  float* swb   = x + 4096;

  hipMemsetAsync(stats1, 0, 6144 * sizeof(float), stream);  // stats1|2|3
  k_pool <<<128, 256, 0, stream>>>(xc, x);
  k_wcvt <<<384, 256, 0, stream>>>(c1w, c2w, w1b, w2p);
  k_order<<<16, 256, 0, stream>>>(ci, x, order, xi, xib);
  k_mlp1 <<<16, 256, 0, stream>>>(xi, mw1, mb1, mw2, mb2, h2mlp);
  k_mlp2 <<<dim3(4, 16), 256, 0, stream>>>(h2mlp, mw3, mb3, swb);
  k_mlp3 <<<dim3(8, 16), 256, 0, stream>>>(swb, gcnw, weff);
  dim3 gconv(72, 16);
  k_conv<0><<<gconv, 256, 0, stream>>>(xi, w1b, w2p, t1, cb2, s42, stats1, stats2, logits);
  k_wsc1 <<<128, 256, 0, stream>>>(stats1, bn1g, bn1b, w1b, w1s, t1);
  k_conv<1><<<gconv, 256, 0, stream>>>(xi, w1s, w2p, t1, cb2, s42, stats1, stats2, logits);
  k_wsc2 <<<384, 256, 0, stream>>>(stats2, bn2g, bn2b, c3w, w2p, w2s, cb2, s42);
  k_conv<2><<<gconv, 256, 0, stream>>>(xi, w1s, w2s, t1, cb2, s42, stats1, stats2, logits);
  k_graph<<<dim3(32, 16), 256, 0, stream>>>(xib, logits, weff, hi, stats3);
  k_bn3  <<<512, 256, 0, stream>>>(hi, stats3, bn3g, bn3b, order, xnew);
  k_final<<<8192, 256, 0, stream>>>(xc, xnew, (float*)d_out);
}

// Round 9
// 123.133 us; speedup vs baseline: 1.4399x; 1.1337x over previous
//
#include <hip/hip_runtime.h>
#include <hip/hip_bf16.h>

// ---------------------------------------------------------------------------
// ClusterGNN fused pipeline for MI355X (gfx950).  Round 9.
//   - 11 dispatches (was 16): k_prep = pool+wcvt+stats-zero; k_mlp = mlp1+2;
//     mlp3 folded into k_graph; memset dropped.
//   - modes 0/1: 1/4 p-sampling on (36,16) grid -> 576 blocks, 1 resident round.
//   - mode 2: (144,16) grid of 16p x 16q blocks -> 2304 blocks = 3 clean rounds.
//   - df fragments precomputed per wave (VALU phase / MFMA phase split).
// ---------------------------------------------------------------------------

typedef short bfrag8 __attribute__((ext_vector_type(8)));   // 8 bf16 (4 VGPR)
typedef float f32x4  __attribute__((ext_vector_type(4)));
typedef int   i32x4  __attribute__((ext_vector_type(4)));
typedef short s4v    __attribute__((ext_vector_type(4)));

#define DI __device__ __forceinline__

DI unsigned short f2bf(float f) {
  return __builtin_bit_cast(unsigned short, __float2bfloat16(f));
}
DI float bf2f(unsigned short u) {
  return __builtin_bit_cast(float, ((unsigned)u) << 16);
}
// pack two floats to two bf16 (round-half-up) in one u32
DI unsigned pack2bf(float lo, float hi) {
  unsigned ulo = __builtin_bit_cast(unsigned, lo) + 0x8000u;
  unsigned uhi = __builtin_bit_cast(unsigned, hi) + 0x8000u;
  return __builtin_amdgcn_perm(uhi, ulo, 0x07060302u);
}

// ------------------------ prep: pool + wcvt + stats zero --------------------
__global__ __launch_bounds__(256) void k_prep(
    const float* __restrict__ xc, float* __restrict__ x,
    const float* __restrict__ w1, const float* __restrict__ w2,
    unsigned short* __restrict__ w1b, unsigned short* __restrict__ w2p,
    float* __restrict__ statsz) {
  const int bid = blockIdx.x, tid = threadIdx.x;
  if (bid < 128) {
    int idx = bid * 256 + tid;      // 32768 float4s
    int c4 = idx & 7, g = idx >> 3;
    int gz = g & 15, gy = (g >> 4) & 15, gx = g >> 8;
    f32x4 s = {0.f, 0.f, 0.f, 0.f};
    for (int ix = 0; ix < 4; ++ix)
      for (int iy = 0; iy < 4; ++iy)
        for (int iz = 0; iz < 4; ++iz) {
          int X = gx * 4 + ix, Y = gy * 4 + iy, Z = gz * 4 + iz;
          s += *(const f32x4*)&xc[(size_t)(((X << 6) | Y) << 6 | Z) * 32 + c4 * 4];
        }
    *(f32x4*)&x[(size_t)idx * 4] = s * (1.f / 64.f);
    if (bid < 24) statsz[bid * 256 + tid] = 0.f;   // stats1|2|3 zero (6144)
  } else {
    int i = (bid - 128) * 256 + tid;               // 98304
    if (i < 32768) w1b[i] = f2bf(w1[i]);
    int o = i >> 6, cc = i & 63;
    int s = cc >> 5, kp = cc & 31;
    int src = 32 * s + 16 * ((kp >> 2) & 1) + 4 * (kp >> 3) + (kp & 3);
    w2p[i] = f2bf(w2[(size_t)o * 64 + src]);
  }
}

// --------------------------- order + gather --------------------------------
__global__ __launch_bounds__(256) void k_order(const int* __restrict__ ci,
                                               const float* __restrict__ x,
                                               int* __restrict__ order,
                                               float* __restrict__ xi,
                                               unsigned short* __restrict__ xib) {
  const int k = blockIdx.x, t = threadIdx.x;
  __shared__ int scnt[256];
  __shared__ int ordl[256];
  int match[16];
  int cnt = 0;
#pragma unroll
  for (int j = 0; j < 16; ++j) { match[j] = (ci[t * 16 + j] == k); cnt += match[j]; }
  scnt[t] = cnt;
  __syncthreads();
  for (int off = 1; off < 256; off <<= 1) {
    int v = (t >= off) ? scnt[t - off] : 0;
    __syncthreads();
    scnt[t] += v;
    __syncthreads();
  }
  int pos = scnt[t] - cnt;
#pragma unroll
  for (int j = 0; j < 16; ++j)
    if (match[j]) ordl[pos++] = t * 16 + j;
  __syncthreads();
  int src = ordl[t];
  order[k * 256 + t] = src;
  const f32x4* xr = (const f32x4*)(x + (size_t)src * 32);
  f32x4* xo = (f32x4*)(xi + ((size_t)k * 256 + t) * 32);
  uint2* xb = (uint2*)(xib + ((size_t)k * 256 + t) * 32);
#pragma unroll
  for (int c = 0; c < 8; ++c) {
    f32x4 v = xr[c];
    xo[c] = v;
    unsigned int lo = f2bf(v[0]) | ((unsigned)f2bf(v[1]) << 16);
    unsigned int hi = f2bf(v[2]) | ((unsigned)f2bf(v[3]) << 16);
    xb[c] = make_uint2(lo, hi);
  }
}

// ------------------------------- MLP (merged 1+2) ---------------------------
__global__ __launch_bounds__(256) void k_mlp(
    const float* __restrict__ xi,
    const float* __restrict__ mw1, const float* __restrict__ mb1,
    const float* __restrict__ mw2, const float* __restrict__ mb2,
    const float* __restrict__ mw3, const float* __restrict__ mb3,
    float* __restrict__ swb) {
  const int k = blockIdx.y, ox = blockIdx.x, t = threadIdx.x;
  __shared__ float red[256];
  __shared__ float cent[32];
  __shared__ float h1[128];
  __shared__ float h2s[256];
  const float* xk = xi + (size_t)k * 8192;
  {
    int c = t & 31, rp = t >> 5;
    float ssum = 0.f;
    for (int r = rp; r < 256; r += 8) ssum += xk[r * 32 + c];
    red[t] = ssum;
  }
  __syncthreads();
  if (t < 32) {
    float tot = 0.f;
#pragma unroll
    for (int g = 0; g < 8; ++g) tot += red[g * 32 + t];
    cent[t] = tot * (1.f / 256.f);
  }
  __syncthreads();
  if (t < 128) {
    float s = mb1[t];
#pragma unroll
    for (int c = 0; c < 32; ++c) s += cent[c] * mw1[c * 128 + t];
    h1[t] = fmaxf(s, 0.f);
  }
  __syncthreads();
  {
    float s = mb2[t];
    for (int j = 0; j < 128; ++j) s += h1[j] * mw2[j * 256 + t];
    h2s[t] = fmaxf(s, 0.f);
  }
  __syncthreads();
  const int o = ox * 256 + t;
  float s = mb3[o];
  for (int j = 0; j < 256; ++j) s += h2s[j] * mw3[j * 1024 + o];
  swb[k * 1024 + o] = 1.f / (1.f + __expf(-s));
}

// --------------------------- fused pair chain -------------------------------
// Swapped MFMA, BN scales folded into weights, BN biases via MFMA C-operand.
//   mode0 (grid 36x16): raw w1b, C=0 -> BN1 stats, p sampled 1/4.
//   mode1 (grid 36x16): w1s + t1 C-in -> a1; raw w2p -> BN2 stats, p 1/4.
//   mode2 (grid 144x16): 16p x 16q blocks, full pairs -> logits (+mirror).
template <int MODE>
__global__ __launch_bounds__(256, (MODE == 0) ? 4 : 3) void k_conv(
    const float* __restrict__ xi,
    const unsigned short* __restrict__ w1x,
    const unsigned short* __restrict__ w2x,
    const float* __restrict__ t1,
    const float* __restrict__ cb2,
    const float* __restrict__ s42,
    float* __restrict__ stats1,
    float* __restrict__ stats2,
    float* __restrict__ logits) {
  const int k   = blockIdx.y;
  const int t36 = (MODE == 2) ? (blockIdx.x >> 2) : blockIdx.x;
  int a = 0, rem = t36;
  while (rem >= 8 - a) { rem -= 8 - a; ++a; }
  const int b = a + rem;                 // a<=b
  const float w = (a == b) ? 1.f : 2.f;

  const int tid = threadIdx.x;
  const int lane = tid & 63;
  const int wv  = tid >> 6;
  const int l15 = lane & 15;
  const int lg  = lane >> 4;

  int Pb0, Qb;
  if constexpr (MODE == 2) {
    const int sub = blockIdx.x & 3;
    Pb0 = a * 32 + (sub >> 1) * 16;
    Qb  = b * 32 + (sub & 1) * 16;
  } else {
    Pb0 = a * 32;
    Qb  = b * 32;
  }

  constexpr int NF  = (MODE == 0) ? 4 : 6;
  constexpr int NCH = NF * 4;
  constexpr int QGN = (MODE == 2) ? 1 : 2;
  constexpr int XPR = (MODE == 2) ? 16 : 32;

  __shared__ __align__(16) float xp[XPR][32];
  __shared__ float sred[192];
  __shared__ __align__(16) float t1s[64];
  __shared__ __align__(16) float cb2s[96];
  __shared__ __align__(16) float s42s[96];

  const float* xik = xi + (size_t)k * 8192;

  if constexpr (MODE == 2) {
    if (tid < 128) {
      int r = tid >> 3, c4 = (tid & 7) * 4;
      *(f32x4*)&xp[r][c4] = *(const f32x4*)(xik + (size_t)(Pb0 + r) * 32 + c4);
    }
  } else {
    int r = tid >> 3, c4 = (tid & 7) * 4;
    *(f32x4*)&xp[r][c4] = *(const f32x4*)(xik + (size_t)(Pb0 + r) * 32 + c4);
  }
  if constexpr (MODE <= 1) {
    if (tid < 192) sred[tid] = 0.f;
  }
  if constexpr (MODE >= 1) {
    if (tid >= 192 && tid < 256) t1s[tid - 192] = t1[k * 64 + tid - 192];
  }
  if constexpr (MODE == 2) {
    if (tid < 96) cb2s[tid] = cb2[k * 96 + tid];
    else if (tid >= 96 && tid < 192) s42s[tid - 96] = s42[k * 96 + tid - 96];
  }

  float qv[QGN][8];
#pragma unroll
  for (int qg = 0; qg < QGN; ++qg) {
    const f32x4* src = (const f32x4*)(xik + (size_t)(Qb + qg * 16 + l15) * 32 + lg * 8);
    f32x4 v0 = src[0], v1 = src[1];
#pragma unroll
    for (int j = 0; j < 4; ++j) { qv[qg][j] = v0[j]; qv[qg][4 + j] = v1[j]; }
  }

  bfrag8 B1[4];
  {
    const unsigned short* w1k = w1x + k * 2048;
#pragma unroll
    for (int f = 0; f < 4; ++f)
      B1[f] = *(const bfrag8*)(w1k + (16 * f + l15) * 32 + lg * 8);
  }
  bfrag8 B2[6][2];
  if constexpr (MODE >= 1) {
    const unsigned short* w2k = w2x + k * 6144;
#pragma unroll
    for (int f2 = 0; f2 < 6; ++f2) {
      B2[f2][0] = *(const bfrag8*)(w2k + (16 * f2 + l15) * 64 + lg * 8);
      B2[f2][1] = *(const bfrag8*)(w2k + (16 * f2 + l15) * 64 + 32 + lg * 8);
    }
  }

  float ss[24], sq[24];
#pragma unroll
  for (int i = 0; i < 24; ++i) { ss[i] = 0.f; sq[i] = 0.f; }

  __syncthreads();

  // ---- phase 1: build all 4 d fragments (pure VALU) ----
  bfrag8 dfa[4];
#pragma unroll
  for (int rp = 0; rp < 4; ++rp) {
    const int pl = (MODE == 2) ? rp : (rp >> 1);
    const int qg = (MODE == 2) ? 0 : (rp & 1);
    const int plocal = (MODE == 2) ? (wv * 4 + pl) : (wv * 8 + pl * 4);
    const float* xpp = &xp[plocal][lg * 8];
    f32x4 p0 = *(const f32x4*)xpp;
    f32x4 p1 = *(const f32x4*)(xpp + 4);
    float pvv[8];
#pragma unroll
    for (int j = 0; j < 4; ++j) { pvv[j] = p0[j]; pvv[4 + j] = p1[j]; }
    unsigned dw[4];
#pragma unroll
    for (int wj = 0; wj < 4; ++wj) {
      float d0 = fabsf(qv[qg][2 * wj]     - pvv[2 * wj]);
      float d1 = fabsf(qv[qg][2 * wj + 1] - pvv[2 * wj + 1]);
      dw[wj] = pack2bf(d0, d1);
    }
    i32x4 dwi = {(int)dw[0], (int)dw[1], (int)dw[2], (int)dw[3]};
    dfa[rp] = __builtin_bit_cast(bfrag8, dwi);
  }

  // ---- phase 2: MFMA chains ----
  const f32x4 z = {0.f, 0.f, 0.f, 0.f};
#pragma unroll
  for (int rp = 0; rp < 4; ++rp) {
    const int pl = (MODE == 2) ? rp : (rp >> 1);
    const int qg = (MODE == 2) ? 0 : (rp & 1);
    const int plocal = (MODE == 2) ? (wv * 4 + pl) : (wv * 8 + pl * 4);
    const int pglob  = Pb0 + plocal;

    f32x4 acc1[4];
    __builtin_amdgcn_s_setprio(1);
#pragma unroll
    for (int f = 0; f < 4; ++f) {
      f32x4 cin;
      if constexpr (MODE == 0) cin = z;
      else cin = *(const f32x4*)&t1s[16 * f + 4 * lg];
      acc1[f] = __builtin_amdgcn_mfma_f32_16x16x32_bf16(B1[f], dfa[rp], cin, 0, 0, 0);
    }
    __builtin_amdgcn_s_setprio(0);

    if constexpr (MODE == 0) {
#pragma unroll
      for (int f = 0; f < 4; ++f)
#pragma unroll
        for (int r = 0; r < 4; ++r) {
          float h = acc1[f][r];
          ss[f * 4 + r] += h; sq[f * 4 + r] = fmaf(h, h, sq[f * 4 + r]);
        }
    } else {
      unsigned paw[8];
#pragma unroll
      for (int f = 0; f < 4; ++f) {
        float h0 = acc1[f][0], h1 = acc1[f][1], h2 = acc1[f][2], h3 = acc1[f][3];
        h0 = fmaxf(h0, 0.2f * h0); h1 = fmaxf(h1, 0.2f * h1);
        h2 = fmaxf(h2, 0.2f * h2); h3 = fmaxf(h3, 0.2f * h3);
        paw[f * 2]     = pack2bf(h0, h1);
        paw[f * 2 + 1] = pack2bf(h2, h3);
      }
      i32x4 pa0i = {(int)paw[0], (int)paw[1], (int)paw[2], (int)paw[3]};
      i32x4 pa1i = {(int)paw[4], (int)paw[5], (int)paw[6], (int)paw[7]};
      bfrag8 pa0 = __builtin_bit_cast(bfrag8, pa0i);
      bfrag8 pa1 = __builtin_bit_cast(bfrag8, pa1i);

      float lp = 0.f;
      __builtin_amdgcn_s_setprio(1);
#pragma unroll
      for (int f2 = 0; f2 < 6; ++f2) {
        f32x4 cin;
        if constexpr (MODE == 2) cin = *(const f32x4*)&cb2s[16 * f2 + 4 * lg];
        else cin = z;
        f32x4 acc = __builtin_amdgcn_mfma_f32_16x16x32_bf16(B2[f2][0], pa0, cin, 0, 0, 0);
        acc = __builtin_amdgcn_mfma_f32_16x16x32_bf16(B2[f2][1], pa1, acc, 0, 0, 0);
        if constexpr (MODE == 1) {
#pragma unroll
          for (int r = 0; r < 4; ++r) {
            float h = acc[r];
            ss[f2 * 4 + r] += h; sq[f2 * 4 + r] = fmaf(h, h, sq[f2 * 4 + r]);
          }
        } else {
          f32x4 s4 = *(const f32x4*)&s42s[16 * f2 + 4 * lg];
#pragma unroll
          for (int r = 0; r < 4; ++r) {
            float aa = acc[r];
            float ab = fmaxf(aa, -aa);
            lp = fmaf(0.6f, aa, lp);
            lp = fmaf(s4[r], ab, lp);
          }
        }
      }
      __builtin_amdgcn_s_setprio(0);
      if constexpr (MODE == 2) {
        lp += __shfl_xor(lp, 16);
        lp += __shfl_xor(lp, 32);
        if (lg == 0) {
          const int q = Qb + l15;
          logits[(size_t)k * 65536 + (size_t)pglob * 256 + q] = lp;
          if (a != b)
            logits[(size_t)k * 65536 + (size_t)q * 256 + pglob] = lp;
        }
      }
    }
  }

  if constexpr (MODE <= 1) {
#pragma unroll
    for (int i = 0; i < NCH; ++i) {
#pragma unroll
      for (int m = 1; m <= 8; m <<= 1) {
        ss[i] += __shfl_xor(ss[i], m);
        sq[i] += __shfl_xor(sq[i], m);
      }
    }
    if (l15 == 0) {
#pragma unroll
      for (int i = 0; i < NCH; ++i) {
        int ch = 16 * (i >> 2) + 4 * lg + (i & 3);
        atomicAdd(&sred[ch * 2 + 0], ss[i] * w);
        atomicAdd(&sred[ch * 2 + 1], sq[i] * w);
      }
    }
    __syncthreads();
    float* gs = (MODE == 0) ? stats1 : stats2;
    if (tid < 2 * 16 * NF) atomicAdd(&gs[k * (2 * 16 * NF) + tid], sred[tid]);
  }
}

// ---------------- BN coef + weight-scale (merged), N = 16384 ----------------
__global__ __launch_bounds__(256) void k_wsc1(
    const float* __restrict__ stats, const float* __restrict__ g,
    const float* __restrict__ b, const unsigned short* __restrict__ w1b,
    unsigned short* __restrict__ w1s, float* __restrict__ t1) {
  int i = blockIdx.x * 256 + threadIdx.x;      // 32768
  int ch = i >> 5;
  float sum = stats[ch * 2], sqv = stats[ch * 2 + 1];
  const float invN = 1.f / 16384.f;
  float mean = sum * invN;
  float var = sqv * invN - mean * mean;
  float s = g[ch] * rsqrtf(fmaxf(var, 0.f) + 1e-5f);
  w1s[i] = f2bf(bf2f(w1b[i]) * s);
  if ((i & 31) == 0) t1[ch] = b[ch] - mean * s;
}

__global__ __launch_bounds__(256) void k_wsc2(
    const float* __restrict__ stats, const float* __restrict__ g,
    const float* __restrict__ b, const float* __restrict__ w3,
    const unsigned short* __restrict__ w2p,
    unsigned short* __restrict__ w2s,
    float* __restrict__ cb2, float* __restrict__ s42) {
  int i = blockIdx.x * 256 + threadIdx.x;      // 98304
  if (i >= 98304) return;
  int o = i >> 6;
  float sum = stats[o * 2], sqv = stats[o * 2 + 1];
  const float invN = 1.f / 16384.f;
  float mean = sum * invN;
  float var = sqv * invN - mean * mean;
  float s = g[o] * rsqrtf(fmaxf(var, 0.f) + 1e-5f);
  float t = b[o] - mean * s;
  float wv = w3[o];
  w2s[i] = f2bf(bf2f(w2p[i]) * (s * wv));
  if ((i & 63) == 0) {
    cb2[o] = t * wv;
    s42[o] = copysignf(0.4f, wv);
  }
}

// --------- softmax + adj@xi + (mlp3-folded) GCN + BN3 stats -----------------
__global__ __launch_bounds__(256) void k_graph(
    const unsigned short* __restrict__ xib,
    const float* __restrict__ logits,
    const float* __restrict__ swb,
    const float* __restrict__ gcnw,
    float* __restrict__ hi,
    float* __restrict__ stats3) {
  const int k  = blockIdx.y;
  const int pc = blockIdx.x;   // 0..31, 8 rows each
  const int tid = threadIdx.x;
  __shared__ __align__(16) unsigned char smem[40960];
  unsigned short* xis = (unsigned short*)smem;       // 256*40 = 20480B
  float* wks  = (float*)(smem + 20480);              // 2048 floats
  float* cbuf = (float*)(smem + 28672);              // 3072 floats

  {  // stage bf16 xi, one row per thread (pad 40 shorts)
    const s4v* src = (const s4v*)(xib + (size_t)k * 8192 + tid * 32);
    s4v* dst = (s4v*)&xis[tid * 40];
#pragma unroll
    for (int j = 0; j < 8; ++j) dst[j] = src[j];
  }
  float* swl = cbuf;          // 1024
  float* gks = cbuf + 1024;   // 2048
#pragma unroll
  for (int j = 0; j < 4; ++j) swl[tid + j * 256] = swb[k * 1024 + tid + j * 256];
#pragma unroll
  for (int j = 0; j < 8; ++j) gks[tid + j * 256] = gcnw[(size_t)k * 2048 + tid + j * 256];
  __syncthreads();

  // mlp3: wks = gcn_w @ sw
#pragma unroll
  for (int j = 0; j < 8; ++j) {
    int e = tid + j * 256;
    int u = e >> 5, v = e & 31;
    float s = 0.f;
#pragma unroll
    for (int c = 0; c < 32; ++c) s += gks[u * 32 + c] * swl[c * 32 + v];
    wks[e] = s;
  }
  __syncthreads();

  float* es    = cbuf;          // [8][260]
  float* axs   = cbuf + 2080;   // [8][34]
  float* inv_s = cbuf + 2352;   // 8
  float* s3    = cbuf + 2360;   // 64
  if (tid < 64) s3[tid] = 0.f;

  const int row = tid >> 5;    // 0..7
  const int s   = tid & 31;
  const int pglob = pc * 8 + row;
  const float* lrow = logits + (size_t)k * 65536 + (size_t)pglob * 256;

  float m = -1e30f;
  for (int q = s; q < 256; q += 32) {
    float v = lrow[q];
    m = (q == pglob) ? m : fmaxf(m, v);
  }
#pragma unroll
  for (int mm = 1; mm < 32; mm <<= 1) m = fmaxf(m, __shfl_xor(m, mm));
  float sum = 0.f;
  for (int q = s; q < 256; q += 32) {
    float e = (q == pglob) ? 0.f : __expf(lrow[q] - m);
    es[row * 260 + q] = e;
    sum += e;
  }
#pragma unroll
  for (int mm = 1; mm < 32; mm <<= 1) sum += __shfl_xor(sum, mm);
  if (s == 0) inv_s[row] = 1.f / sum;
  __syncthreads();

  float a0 = 0.f;
  for (int q = 0; q < 256; ++q)
    a0 += es[row * 260 + q] * bf2f(xis[q * 40 + s]);
  axs[row * 34 + s] = a0 * inv_s[row];
  __syncthreads();

  float h = 0.f;
  for (int u = 0; u < 32; ++u) {
    float xu = bf2f(xis[pglob * 40 + u]);
    float au = axs[row * 34 + u];
    h += xu * wks[u * 32 + s] + au * wks[(32 + u) * 32 + s];
  }
  float v = fmaxf(h, 0.2f * h);
  hi[(size_t)k * 8192 + (size_t)pglob * 32 + s] = v;
  float vs = v, vq = v * v;
  vs += __shfl_xor(vs, 32);
  vq += __shfl_xor(vq, 32);
  if ((tid & 32) == 0) {
    atomicAdd(&s3[s * 2 + 0], vs);
    atomicAdd(&s3[s * 2 + 1], vq);
  }
  __syncthreads();
  if (tid < 64) atomicAdd(&stats3[k * 64 + tid], s3[tid]);
}

// ------------------------------ BN3 + scatter -------------------------------
__global__ __launch_bounds__(256) void k_bn3(
    const float* __restrict__ hi, const float* __restrict__ stats3,
    const float* __restrict__ g3, const float* __restrict__ b3,
    const int* __restrict__ order, float* __restrict__ xnew) {
  int idx = blockIdx.x * 256 + threadIdx.x;   // 131072
  int k = idx >> 13, r = (idx >> 5) & 255, c = idx & 31;
  float sum = stats3[k * 64 + c * 2], sqv = stats3[k * 64 + c * 2 + 1];
  const float invN = 1.f / 256.f;
  float mean = sum * invN;
  float var = sqv * invN - mean * mean;
  float s = g3[k * 32 + c] * rsqrtf(fmaxf(var, 0.f) + 1e-5f);
  float t = b3[k * 32 + c] - mean * s;
  xnew[(size_t)order[k * 256 + r] * 32 + c] = hi[idx] * s + t;
}

// ------------------------------- final add ----------------------------------
__global__ __launch_bounds__(256) void k_final(const float* __restrict__ xc,
                                               const float* __restrict__ xnew,
                                               float* __restrict__ out) {
  int idx = blockIdx.x * 256 + threadIdx.x;   // 2097152 float4 groups
  int c4 = idx & 7, v = idx >> 3;
  int z = v & 63, y = (v >> 6) & 63, x = v >> 12;
  int sx = (x >> 2) + (x & 3) - 1;
  int sy = (y >> 2) + (y & 3) - 1;
  int sz = (z >> 2) + (z & 3) - 1;
  f32x4 add = {0.f, 0.f, 0.f, 0.f};
  if ((unsigned)sx < 16u && (unsigned)sy < 16u && (unsigned)sz < 16u)
    add = *(const f32x4*)&xnew[(size_t)(((sx << 4) + sy) * 16 + sz) * 32 + c4 * 4];
  const f32x4 a = *(const f32x4*)&xc[(size_t)idx * 4];
  *(f32x4*)&out[(size_t)idx * 4] = a + add;
}

// ----------------------------------------------------------------------------
extern "C" void kernel_launch(void* const* d_in, const int* in_sizes, int n_in,
                              void* d_out, int out_size, void* d_ws, size_t ws_size,
                              hipStream_t stream) {
  const float* xc   = (const float*)d_in[0];
  const int*   ci   = (const int*)  d_in[1];
  const float* c1w  = (const float*)d_in[2];
  const float* bn1g = (const float*)d_in[4];
  const float* bn1b = (const float*)d_in[5];
  const float* c2w  = (const float*)d_in[6];
  const float* bn2g = (const float*)d_in[8];
  const float* bn2b = (const float*)d_in[9];
  const float* c3w  = (const float*)d_in[10];
  const float* gcnw = (const float*)d_in[12];
  const float* bn3g = (const float*)d_in[13];
  const float* bn3b = (const float*)d_in[14];
  const float* mw1  = (const float*)d_in[15];
  const float* mb1  = (const float*)d_in[16];
  const float* mw2  = (const float*)d_in[17];
  const float* mb2  = (const float*)d_in[18];
  const float* mw3  = (const float*)d_in[19];
  const float* mb3  = (const float*)d_in[20];

  float* wsf = (float*)d_ws;
  float*  x      = wsf + 0;          // 131072 (dead after k_order; reused)
  float*  xi     = wsf + 131072;     // 131072
  float*  xnew   = wsf + 262144;     // 131072
  float*  hi     = wsf + 393216;     // 131072
  float*  stats1 = wsf + 557056;     // 2048
  float*  stats2 = wsf + 559104;     // 3072
  float*  stats3 = wsf + 562176;     // 1024
  float*  t1     = wsf + 563200;     // 1024
  float*  cb2    = wsf + 564224;     // 1536
  float*  s42    = wsf + 565760;     // 1536
  float*  logits = wsf + 567296;     // 1048576
  unsigned char* wsb = (unsigned char*)d_ws;
  int* order = (int*)(wsb + 6463488);
  unsigned short* w1b = (unsigned short*)(wsb + 6463488 + 16384);
  unsigned short* w2p = (unsigned short*)(wsb + 6463488 + 16384 + 65536);
  unsigned short* w1s = (unsigned short*)(wsb + 6463488 + 16384 + 65536 + 196608);
  unsigned short* w2s = (unsigned short*)(wsb + 6463488 + 16384 + 65536 + 196608 + 65536);
  unsigned short* xib = (unsigned short*)(wsb + 6463488 + 16384 + 65536 + 196608 + 65536 + 196608);
  float* swb = x + 4096;             // 16384 floats, alias dead x region

  k_prep <<<512, 256, 0, stream>>>(xc, x, c1w, c2w, w1b, w2p, stats1);
  k_order<<<16, 256, 0, stream>>>(ci, x, order, xi, xib);
  k_mlp  <<<dim3(4, 16), 256, 0, stream>>>(xi, mw1, mb1, mw2, mb2, mw3, mb3, swb);
  k_conv<0><<<dim3(36, 16), 256, 0, stream>>>(xi, w1b, w2p, t1, cb2, s42, stats1, stats2, logits);
  k_wsc1 <<<128, 256, 0, stream>>>(stats1, bn1g, bn1b, w1b, w1s, t1);
  k_conv<1><<<dim3(36, 16), 256, 0, stream>>>(xi, w1s, w2p, t1, cb2, s42, stats1, stats2, logits);
  k_wsc2 <<<384, 256, 0, stream>>>(stats2, bn2g, bn2b, c3w, w2p, w2s, cb2, s42);
  k_conv<2><<<dim3(144, 16), 256, 0, stream>>>(xi, w1s, w2s, t1, cb2, s42, stats1, stats2, logits);
  k_graph<<<dim3(32, 16), 256, 0, stream>>>(xib, logits, swb, gcnw, hi, stats3);
  k_bn3  <<<512, 256, 0, stream>>>(hi, stats3, bn3g, bn3b, order, xnew);
  k_final<<<8192, 256, 0, stream>>>(xc, xnew, (float*)d_out);
}